// Round 2
// baseline (341.826 us; speedup 1.0000x reference)
//
#include <hip/hip_runtime.h>
#include <math.h>

typedef __bf16 bf16_t;
typedef bf16_t bf16x8 __attribute__((ext_vector_type(8)));
typedef bf16_t bf16x4 __attribute__((ext_vector_type(4)));
typedef float  floatx4 __attribute__((ext_vector_type(4)));
typedef unsigned int u32;

#define MFMA_BF16(a, b, c) __builtin_amdgcn_mfma_f32_16x16x32_bf16((a), (b), (c), 0, 0, 0)

static constexpr int DMODEL = 1024;
static constexpr int NHEAD  = 16;
static constexpr int HDIM   = 64;
static constexpr int NBATCH = 4;
static constexpr int SEQLEN = 1024;
static constexpr int NTOK   = NBATCH * SEQLEN;  // 4096

typedef __attribute__((address_space(3))) void       as3_void;
typedef __attribute__((address_space(1))) const void as1_cvoid;

// async global->LDS, 16B/lane; LDS dest = wave-uniform base + lane*16
__device__ __forceinline__ void gload16(const void* g, void* l) {
    __builtin_amdgcn_global_load_lds((as1_cvoid*)g, (as3_void*)l, 16, 0, 0);
}

// load 8 consecutive fp32, round to bf16x8
__device__ __forceinline__ bf16x8 load_cvt8(const float* __restrict__ p) {
    floatx4 a = *(const floatx4*)p;
    floatx4 b = *(const floatx4*)(p + 4);
    bf16x8 r;
    r[0] = (bf16_t)a[0]; r[1] = (bf16_t)a[1]; r[2] = (bf16_t)a[2]; r[3] = (bf16_t)a[3];
    r[4] = (bf16_t)b[0]; r[5] = (bf16_t)b[1]; r[6] = (bf16_t)b[2]; r[7] = (bf16_t)b[3];
    return r;
}

// ---------------- fused prep: z=0..3 transpose+cvt W_z; z=4..6 cvt q/k/v ----------------
__global__ __launch_bounds__(256) void prep(
    const float* __restrict__ W0, const float* __restrict__ W1,
    const float* __restrict__ W2, const float* __restrict__ W3,
    const float* __restrict__ q, const float* __restrict__ k, const float* __restrict__ v,
    bf16_t* __restrict__ Wt, bf16_t* __restrict__ Xr)
{
    __shared__ float tile[32][33];
    const int z = blockIdx.z;
    if (z < 4) {
        const float* W = (z == 0) ? W0 : (z == 1) ? W1 : (z == 2) ? W2 : W3;
        bf16_t* O = Wt + (size_t)z * DMODEL * DMODEL;
        const int tx = threadIdx.x & 31, ty = threadIdx.x >> 5;   // 32 x 8
        const int r0 = blockIdx.x * 32, c0 = blockIdx.y * 32;
#pragma unroll
        for (int i = 0; i < 32; i += 8)
            tile[ty + i][tx] = W[(size_t)(r0 + ty + i) * DMODEL + c0 + tx];
        __syncthreads();
#pragma unroll
        for (int i = 0; i < 32; i += 8)
            O[(size_t)(c0 + ty + i) * DMODEL + r0 + tx] = (bf16_t)tile[tx][ty + i];
    } else {
        const float* src = (z == 4) ? q : (z == 5) ? k : v;
        bf16_t* dst = Xr + (size_t)(z - 4) * ((size_t)NTOK * DMODEL);
        size_t i = (((size_t)blockIdx.y * 32 + blockIdx.x) * 256 + threadIdx.x) * 16;
        *(bf16x8*)(dst + i)     = load_cvt8(src + i);
        *(bf16x8*)(dst + i + 8) = load_cvt8(src + i + 8);
    }
}

// ---------------- fallback-path kernels (ws < 56 MB) ----------------
__global__ __launch_bounds__(256) void transpose_w(
    const float* __restrict__ W0, const float* __restrict__ W1,
    const float* __restrict__ W2, const float* __restrict__ W3,
    bf16_t* __restrict__ out)
{
    __shared__ float tile[32][33];
    const float* W = (blockIdx.z == 0) ? W0 : (blockIdx.z == 1) ? W1
                   : (blockIdx.z == 2) ? W2 : W3;
    bf16_t* O = out + (size_t)blockIdx.z * DMODEL * DMODEL;
    int tx = threadIdx.x, ty = threadIdx.y;           // 32 x 8
    int r0 = blockIdx.x * 32, c0 = blockIdx.y * 32;
#pragma unroll
    for (int i = 0; i < 32; i += 8)
        tile[ty + i][tx] = W[(size_t)(r0 + ty + i) * DMODEL + c0 + tx];
    __syncthreads();
#pragma unroll
    for (int i = 0; i < 32; i += 8)
        O[(size_t)(c0 + ty + i) * DMODEL + r0 + tx] = (bf16_t)tile[tx][ty + i];
}
__global__ __launch_bounds__(256) void cvt_bf16(
    const float* __restrict__ src, bf16_t* __restrict__ dst)
{
    size_t i = ((size_t)blockIdx.x * 256 + threadIdx.x) * 8;
    *(bf16x8*)(dst + i) = load_cvt8(src + i);
}

// ---------------- QKV projection GEMM, 128x128 tile, BK=32, dbuf single-barrier ----------------
__global__ __launch_bounds__(256) void gemm_qkv(
    const bf16_t* __restrict__ Xb, size_t astride, int mode0,
    const bf16_t* __restrict__ Wt,
    const float* __restrict__ bq, const float* __restrict__ bk, const float* __restrict__ bv,
    bf16_t* __restrict__ Qh, bf16_t* __restrict__ Kh, bf16_t* __restrict__ Vt)
{
    const int mode = mode0 + blockIdx.z;
    const bf16_t* A = Xb + astride * (size_t)blockIdx.z;
    const bf16_t* B = Wt + (size_t)mode * DMODEL * DMODEL;
    const float* bias = (mode == 0) ? bq : (mode == 1) ? bk : bv;
    bf16_t* out       = (mode == 0) ? Qh : (mode == 1) ? Kh : Vt;

    __shared__ __align__(16) bf16_t lA[2][128 * 32];
    __shared__ __align__(16) bf16_t lB[2][128 * 32];

    const int wave = threadIdx.x >> 6, lane = threadIdx.x & 63;
    const int quad = lane >> 4, l15 = lane & 15;
    const int wm = wave >> 1, wn = wave & 1;
    const int row0 = blockIdx.x * 128, col0 = blockIdx.y * 128;
    const int srow = lane >> 2, scol = (lane & 3) * 8;

    const floatx4 zero = {0.f, 0.f, 0.f, 0.f};
    floatx4 acc[4][4];
#pragma unroll
    for (int mt = 0; mt < 4; mt++)
#pragma unroll
        for (int nt = 0; nt < 4; nt++) acc[mt][nt] = zero;

#pragma unroll
    for (int j = 0; j < 2; j++) {
        const int seg = j * 4 + wave;
        gload16(A + (size_t)(row0 + seg * 16 + srow) * DMODEL + scol, lA[0] + seg * 512);
        gload16(B + (size_t)(col0 + seg * 16 + srow) * DMODEL + scol, lB[0] + seg * 512);
    }

    for (int it = 0; it < 32; it++) {
        __syncthreads();
        const int cur = it & 1;
        if (it + 1 < 32) {
            const int k1 = (it + 1) * 32;
            const int nb = cur ^ 1;
#pragma unroll
            for (int j = 0; j < 2; j++) {
                const int seg = j * 4 + wave;
                gload16(A + (size_t)(row0 + seg * 16 + srow) * DMODEL + k1 + scol, lA[nb] + seg * 512);
                gload16(B + (size_t)(col0 + seg * 16 + srow) * DMODEL + k1 + scol, lB[nb] + seg * 512);
            }
        }
        bf16x8 aF[4], bF[4];
#pragma unroll
        for (int t = 0; t < 4; t++) {
            aF[t] = *(const bf16x8*)(lA[cur] + (wm * 64 + t * 16 + l15) * 32 + quad * 8);
            bF[t] = *(const bf16x8*)(lB[cur] + (wn * 64 + t * 16 + l15) * 32 + quad * 8);
        }
#pragma unroll
        for (int mt = 0; mt < 4; mt++)
#pragma unroll
            for (int nt = 0; nt < 4; nt++)
                acc[mt][nt] = MFMA_BF16(aF[mt], bF[nt], acc[mt][nt]);
    }

#pragma unroll
    for (int nt = 0; nt < 4; nt++) {
        const int gn = col0 + wn * 64 + nt * 16 + l15;
        const float bb = bias[gn];
        const int hh = gn >> 6, dd = gn & 63;
#pragma unroll
        for (int mt = 0; mt < 4; mt++) {
#pragma unroll
            for (int r = 0; r < 4; r++) {
                const int tok = row0 + wm * 64 + mt * 16 + quad * 4 + r;
                const int b = tok >> 10, s = tok & 1023;
                float vv = acc[mt][nt][r] + bb;
                size_t addr;
                if (mode == 2) {
                    addr = ((size_t)((b * NHEAD + hh) * HDIM + dd)) * SEQLEN + s;
                } else {
                    if (mode == 0) vv *= 0.125f;  // 1/sqrt(Dk), exact pow2
                    addr = ((size_t)((b * NHEAD + hh) * SEQLEN + s)) * HDIM + dd;
                }
                out[addr] = (bf16_t)vv;
            }
        }
    }
}

// ---------------- output projection GEMM, 64x128 tile, dbuf single-barrier ----------------
__global__ __launch_bounds__(256) void gemm_o(
    const bf16_t* __restrict__ Xa, const bf16_t* __restrict__ Wt,
    const float* __restrict__ bias, float* __restrict__ out)
{
    __shared__ __align__(16) bf16_t lA[2][64 * 32];
    __shared__ __align__(16) bf16_t lB[2][128 * 32];

    const int wave = threadIdx.x >> 6, lane = threadIdx.x & 63;
    const int quad = lane >> 4, l15 = lane & 15;
    const int wm = wave & 1, wn = wave >> 1;
    const int row0 = blockIdx.x * 64, col0 = blockIdx.y * 128;
    const int srow = lane >> 2, scol = (lane & 3) * 8;

    const floatx4 zero = {0.f, 0.f, 0.f, 0.f};
    floatx4 acc[2][4];
#pragma unroll
    for (int mt = 0; mt < 2; mt++)
#pragma unroll
        for (int nt = 0; nt < 4; nt++) acc[mt][nt] = zero;

    gload16(Xa + (size_t)(row0 + wave * 16 + srow) * DMODEL + scol, lA[0] + wave * 512);
#pragma unroll
    for (int j = 0; j < 2; j++) {
        const int seg = wave * 2 + j;
        gload16(Wt + (size_t)(col0 + seg * 16 + srow) * DMODEL + scol, lB[0] + seg * 512);
    }

    for (int it = 0; it < 32; it++) {
        __syncthreads();
        const int cur = it & 1;
        if (it + 1 < 32) {
            const int k1 = (it + 1) * 32;
            const int nb = cur ^ 1;
            gload16(Xa + (size_t)(row0 + wave * 16 + srow) * DMODEL + k1 + scol, lA[nb] + wave * 512);
#pragma unroll
            for (int j = 0; j < 2; j++) {
                const int seg = wave * 2 + j;
                gload16(Wt + (size_t)(col0 + seg * 16 + srow) * DMODEL + k1 + scol, lB[nb] + seg * 512);
            }
        }
        bf16x8 aF[2], bF[4];
#pragma unroll
        for (int t = 0; t < 2; t++)
            aF[t] = *(const bf16x8*)(lA[cur] + (wm * 32 + t * 16 + l15) * 32 + quad * 8);
#pragma unroll
        for (int t = 0; t < 4; t++)
            bF[t] = *(const bf16x8*)(lB[cur] + (wn * 64 + t * 16 + l15) * 32 + quad * 8);
#pragma unroll
        for (int mt = 0; mt < 2; mt++)
#pragma unroll
            for (int nt = 0; nt < 4; nt++)
                acc[mt][nt] = MFMA_BF16(aF[mt], bF[nt], acc[mt][nt]);
    }

#pragma unroll
    for (int nt = 0; nt < 4; nt++) {
        const int gn = col0 + wn * 64 + nt * 16 + l15;
        const float bb = bias[gn];
#pragma unroll
        for (int mt = 0; mt < 2; mt++) {
#pragma unroll
            for (int r = 0; r < 4; r++) {
                const int tok = row0 + wm * 32 + mt * 16 + quad * 4 + r;
                out[(size_t)tok * DMODEL + gn] = acc[mt][nt][r] + bb;
            }
        }
    }
}

// ---------------- causal flash attention: K-split x4, pair-balanced, no online max ----------
// v3: one pair-tile per block, 4 waves split key-chunks by (kc mod 4). Grid 1024->2048
// blocks => 8 blocks/CU x 4 waves = 32 waves/CU (was 16): TLP now hides the L2-resident
// K-load latency that ILP prefetch (v2) could not (compiler sank the loads, VGPR stayed 64).
// Partials are additive (no online max): 2-stage LDS tree combine (1,3 -> 0,2; then 2 -> 0).
#define SOFTMAX_PV(S0x, S1x, qbase, qrow, lacc, oacc) do {                             \
    const bool nomask = (kb + 31 <= (qbase));                                          \
    float ps = 0.f;                                                                    \
    union { bf16_t hh2[8]; u32 u[4]; } pk;                                             \
    _Pragma("unroll") for (int r = 0; r < 4; r++) {                                    \
        const int key0 = kb + quad * 4 + r;                                            \
        float s0 = (nomask || key0 <= (qrow))      ? S0x[r] : -1e30f;                  \
        float s1 = (nomask || key0 + 16 <= (qrow)) ? S1x[r] : -1e30f;                  \
        float e0 = __expf(s0), e1 = __expf(s1);                                        \
        ps += e0 + e1;                                                                 \
        pk.hh2[r] = (bf16_t)e0; pk.hh2[4 + r] = (bf16_t)e1;                            \
    }                                                                                  \
    lacc += ps;                                                                        \
    u32 a0 = __shfl(pk.u[0], srcA), a1 = __shfl(pk.u[1], srcA);                        \
    u32 a2 = __shfl(pk.u[0], srcB), a3 = __shfl(pk.u[1], srcB);                        \
    u32 b0 = __shfl(pk.u[2], srcA), b1 = __shfl(pk.u[3], srcA);                        \
    u32 b2 = __shfl(pk.u[2], srcB), b3 = __shfl(pk.u[3], srcB);                        \
    union { u32 u[4]; bf16x8 v; } bP;                                                  \
    bP.u[0] = hiP ? b0 : a0; bP.u[1] = hiP ? b1 : a1;                                  \
    bP.u[2] = hiP ? b2 : a2; bP.u[3] = hiP ? b3 : a3;                                  \
    _Pragma("unroll") for (int dt = 0; dt < 4; dt++)                                   \
        oacc[dt] = MFMA_BF16(Vv[dt], bP.v, oacc[dt]);                                  \
} while (0)

__global__ __launch_bounds__(256, 8) void attn(
    const bf16_t* __restrict__ Qh, const bf16_t* __restrict__ Kh,
    const bf16_t* __restrict__ Vt, bf16_t* __restrict__ X)
{
    __shared__ __align__(8) float comb[2][64][34];     // partial publish: 32 o + 2 l
    const int wave = threadIdx.x >> 6, lane = threadIdx.x & 63;
    const int quad = lane >> 4, l15 = lane & 15;
    const int L = blockIdx.x;                          // [0,2048)
    const int bh = (L & 7) * 8 + ((L >> 3) & 7);       // 8 heads per XCD
    const int t  = L >> 6;                             // pair index [0,32)
    const int b = bh >> 4, h = bh & 15;

    const int qbaseA = 16 * t, qbaseB = 1008 - 16 * t;
    const int qrowA = qbaseA + l15, qrowB = qbaseB + l15;
    const int nkA = t / 2 + 1, nkB = 32 - t / 2;

    const bf16_t* Qp = Qh + (size_t)bh * SEQLEN * HDIM;
    const bf16_t* Kp = Kh + (size_t)bh * SEQLEN * HDIM;
    const bf16_t* Vp = Vt + (size_t)bh * HDIM * SEQLEN;

    bf16x8 bQA[2], bQB[2];
#pragma unroll
    for (int c = 0; c < 2; c++) {
        bQA[c] = *(const bf16x8*)(Qp + (size_t)qrowA * HDIM + c * 32 + quad * 8);
        bQB[c] = *(const bf16x8*)(Qp + (size_t)qrowB * HDIM + c * 32 + quad * 8);
    }

    const floatx4 zero = {0.f, 0.f, 0.f, 0.f};
    float lA_ = 0.f, lB_ = 0.f;
    floatx4 oA[4], oB[4];
#pragma unroll
    for (int dt = 0; dt < 4; dt++) { oA[dt] = zero; oB[dt] = zero; }

    const int srcA = ((quad & 1) ? 32 : 0) + l15;      // P-transpose shuffle sources
    const int srcB = srcA + 16;
    const bool hiP = (quad >= 2);

    for (int kc = wave; kc < nkB; kc += 4) {
        const int kb = kc * 32;
        bf16x8 K0[2], K1[2], Vv[4];
#pragma unroll
        for (int c = 0; c < 2; c++) {
            K0[c] = *(const bf16x8*)(Kp + (size_t)(kb + l15) * HDIM + c * 32 + quad * 8);
            K1[c] = *(const bf16x8*)(Kp + (size_t)(kb + 16 + l15) * HDIM + c * 32 + quad * 8);
        }
#pragma unroll
        for (int dt = 0; dt < 4; dt++)
            Vv[dt] = *(const bf16x8*)(Vp + (size_t)(dt * 16 + l15) * SEQLEN + kb + quad * 8);

        const bool doA = (kc < nkA);                   // wave-uniform
        floatx4 S0B = zero, S1B = zero, S0A = zero, S1A = zero;
#pragma unroll
        for (int c = 0; c < 2; c++) {
            S0B = MFMA_BF16(K0[c], bQB[c], S0B);
            S1B = MFMA_BF16(K1[c], bQB[c], S1B);
        }
        if (doA) {
#pragma unroll
            for (int c = 0; c < 2; c++) {
                S0A = MFMA_BF16(K0[c], bQA[c], S0A);
                S1A = MFMA_BF16(K1[c], bQA[c], S1A);
            }
        }
        SOFTMAX_PV(S0B, S1B, qbaseB, qrowB, lB_, oB);
        if (doA) { SOFTMAX_PV(S0A, S1A, qbaseA, qrowA, lA_, oA); }
    }

    // 2-stage partial combine through LDS: waves 1,3 -> 0,2; then wave 2 -> 0.
    auto publish = [&](int slot) {
        float2* d2 = (float2*)&comb[slot][lane][0];
#pragma unroll
        for (int dt = 0; dt < 4; dt++) {
            d2[2 * dt]     = make_float2(oA[dt][0], oA[dt][1]);
            d2[2 * dt + 1] = make_float2(oA[dt][2], oA[dt][3]);
            d2[8 + 2 * dt]     = make_float2(oB[dt][0], oB[dt][1]);
            d2[8 + 2 * dt + 1] = make_float2(oB[dt][2], oB[dt][3]);
        }
        d2[16] = make_float2(lA_, lB_);
    };
    auto accum = [&](int slot) {
        const float2* s2 = (const float2*)&comb[slot][lane][0];
#pragma unroll
        for (int dt = 0; dt < 4; dt++) {
            float2 x0 = s2[2 * dt], x1 = s2[2 * dt + 1];
            float2 y0 = s2[8 + 2 * dt], y1 = s2[8 + 2 * dt + 1];
            oA[dt][0] += x0.x; oA[dt][1] += x0.y; oA[dt][2] += x1.x; oA[dt][3] += x1.y;
            oB[dt][0] += y0.x; oB[dt][1] += y0.y; oB[dt][2] += y1.x; oB[dt][3] += y1.y;
        }
        float2 lp = s2[16];
        lA_ += lp.x; lB_ += lp.y;
    };

    if (wave & 1) publish(wave >> 1);                  // 1 -> slot 0, 3 -> slot 1
    __syncthreads();
    if (!(wave & 1)) accum(wave >> 1);                 // 0 += slot 0, 2 += slot 1
    __syncthreads();
    if (wave == 2) publish(0);
    __syncthreads();
    if (wave == 0) {
        accum(0);

        lA_ += __shfl_xor(lA_, 16); lA_ += __shfl_xor(lA_, 32);
        lB_ += __shfl_xor(lB_, 16); lB_ += __shfl_xor(lB_, 32);

        const float invA = 1.f / lA_, invB = 1.f / lB_;
#pragma unroll
        for (int dt = 0; dt < 4; dt++) {
            bf16x4 va, vb;
#pragma unroll
            for (int r = 0; r < 4; r++) {
                va[r] = (bf16_t)(oA[dt][r] * invA);
                vb[r] = (bf16_t)(oB[dt][r] * invB);
            }
            const size_t cofs = (size_t)h * HDIM + dt * 16 + quad * 4;
            *(bf16x4*)(&X[((size_t)(b * SEQLEN + qrowA)) * DMODEL + cofs]) = va;
            *(bf16x4*)(&X[((size_t)(b * SEQLEN + qrowB)) * DMODEL + cofs]) = vb;
        }
    }
}

extern "C" void kernel_launch(void* const* d_in, const int* in_sizes, int n_in,
                              void* d_out, int out_size, void* d_ws, size_t ws_size,
                              hipStream_t stream)
{
    const float* q  = (const float*)d_in[0];
    const float* k  = (const float*)d_in[1];
    const float* v  = (const float*)d_in[2];
    // d_in[3] = causal mask (deterministic tril) — applied analytically
    const float* Wq = (const float*)d_in[4];
    const float* bq = (const float*)d_in[5];
    const float* Wk = (const float*)d_in[6];
    const float* bk = (const float*)d_in[7];
    const float* Wv = (const float*)d_in[8];
    const float* bv = (const float*)d_in[9];
    const float* Wo = (const float*)d_in[10];
    const float* bo = (const float*)d_in[11];
    float* out = (float*)d_out;

    char* ws = (char*)d_ws;
    const size_t MB = 1ull << 20;
    const size_t NELEM = (size_t)NTOK * DMODEL;            // 4M elements / 8 MB bf16
    bf16_t* Wt = (bf16_t*)ws;                              // [0,8) MB
    bf16_t* Qh = (bf16_t*)(ws + 8 * MB);                   // [8,16)
    bf16_t* Kh = (bf16_t*)(ws + 16 * MB);                  // [16,24)
    bf16_t* Vt = (bf16_t*)(ws + 24 * MB);                  // [24,32)
    bf16_t* Xr = (bf16_t*)(ws + 32 * MB);                  // [32,...) staging; Xa overlays

    if (ws_size >= 56 * MB) {
        prep<<<dim3(32, 32, 7), dim3(256), 0, stream>>>(Wq, Wk, Wv, Wo, q, k, v, Wt, Xr);
        gemm_qkv<<<dim3(32, 8, 3), dim3(256), 0, stream>>>(
            Xr, NELEM, 0, Wt, bq, bk, bv, Qh, Kh, Vt);
    } else {
        transpose_w<<<dim3(32, 32, 4), dim3(32, 8), 0, stream>>>(Wq, Wk, Wv, Wo, Wt);
        const float* qkv_in[3] = {q, k, v};
        for (int m = 0; m < 3; m++) {
            cvt_bf16<<<dim3(2048), dim3(256), 0, stream>>>(qkv_in[m], Xr);
            gemm_qkv<<<dim3(32, 8, 1), dim3(256), 0, stream>>>(
                Xr, 0, m, Wt, bq, bk, bv, Qh, Kh, Vt);
        }
    }

    bf16_t* Xa = Xr;   // overlay q's bf16 copy (dead after gemm_qkv)
    attn<<<dim3(2048), dim3(256), 0, stream>>>(Qh, Kh, Vt, Xa);
    gemm_o<<<dim3(64, 8), dim3(256), 0, stream>>>(
        Xa, Wt + 3 * (size_t)DMODEL * DMODEL, bo, out);
}

// Round 3
// 238.023 us; speedup vs baseline: 1.4361x; 1.4361x over previous
//
#include <hip/hip_runtime.h>
#include <math.h>

typedef __bf16 bf16_t;
typedef bf16_t bf16x8 __attribute__((ext_vector_type(8)));
typedef bf16_t bf16x4 __attribute__((ext_vector_type(4)));
typedef float  floatx4 __attribute__((ext_vector_type(4)));
typedef unsigned int u32;

#define MFMA_BF16(a, b, c) __builtin_amdgcn_mfma_f32_16x16x32_bf16((a), (b), (c), 0, 0, 0)

static constexpr int DMODEL = 1024;
static constexpr int NHEAD  = 16;
static constexpr int HDIM   = 64;
static constexpr int NBATCH = 4;
static constexpr int SEQLEN = 1024;
static constexpr int NTOK   = NBATCH * SEQLEN;  // 4096

typedef __attribute__((address_space(3))) void       as3_void;
typedef __attribute__((address_space(1))) const void as1_cvoid;

// async global->LDS, 16B/lane; LDS dest = wave-uniform base + lane*16
__device__ __forceinline__ void gload16(const void* g, void* l) {
    __builtin_amdgcn_global_load_lds((as1_cvoid*)g, (as3_void*)l, 16, 0, 0);
}

// load 8 consecutive fp32, round to bf16x8
__device__ __forceinline__ bf16x8 load_cvt8(const float* __restrict__ p) {
    floatx4 a = *(const floatx4*)p;
    floatx4 b = *(const floatx4*)(p + 4);
    bf16x8 r;
    r[0] = (bf16_t)a[0]; r[1] = (bf16_t)a[1]; r[2] = (bf16_t)a[2]; r[3] = (bf16_t)a[3];
    r[4] = (bf16_t)b[0]; r[5] = (bf16_t)b[1]; r[6] = (bf16_t)b[2]; r[7] = (bf16_t)b[3];
    return r;
}

// ---------------- fused prep: z=0..3 transpose+cvt W_z; z=4..6 cvt q/k/v ----------------
__global__ __launch_bounds__(256) void prep(
    const float* __restrict__ W0, const float* __restrict__ W1,
    const float* __restrict__ W2, const float* __restrict__ W3,
    const float* __restrict__ q, const float* __restrict__ k, const float* __restrict__ v,
    bf16_t* __restrict__ Wt, bf16_t* __restrict__ Xr)
{
    __shared__ float tile[32][33];
    const int z = blockIdx.z;
    if (z < 4) {
        const float* W = (z == 0) ? W0 : (z == 1) ? W1 : (z == 2) ? W2 : W3;
        bf16_t* O = Wt + (size_t)z * DMODEL * DMODEL;
        const int tx = threadIdx.x & 31, ty = threadIdx.x >> 5;   // 32 x 8
        const int r0 = blockIdx.x * 32, c0 = blockIdx.y * 32;
#pragma unroll
        for (int i = 0; i < 32; i += 8)
            tile[ty + i][tx] = W[(size_t)(r0 + ty + i) * DMODEL + c0 + tx];
        __syncthreads();
#pragma unroll
        for (int i = 0; i < 32; i += 8)
            O[(size_t)(c0 + ty + i) * DMODEL + r0 + tx] = (bf16_t)tile[tx][ty + i];
    } else {
        const float* src = (z == 4) ? q : (z == 5) ? k : v;
        bf16_t* dst = Xr + (size_t)(z - 4) * ((size_t)NTOK * DMODEL);
        size_t i = (((size_t)blockIdx.y * 32 + blockIdx.x) * 256 + threadIdx.x) * 16;
        *(bf16x8*)(dst + i)     = load_cvt8(src + i);
        *(bf16x8*)(dst + i + 8) = load_cvt8(src + i + 8);
    }
}

// ---------------- fallback-path kernels (ws < 56 MB) ----------------
__global__ __launch_bounds__(256) void transpose_w(
    const float* __restrict__ W0, const float* __restrict__ W1,
    const float* __restrict__ W2, const float* __restrict__ W3,
    bf16_t* __restrict__ out)
{
    __shared__ float tile[32][33];
    const float* W = (blockIdx.z == 0) ? W0 : (blockIdx.z == 1) ? W1
                   : (blockIdx.z == 2) ? W2 : W3;
    bf16_t* O = out + (size_t)blockIdx.z * DMODEL * DMODEL;
    int tx = threadIdx.x, ty = threadIdx.y;           // 32 x 8
    int r0 = blockIdx.x * 32, c0 = blockIdx.y * 32;
#pragma unroll
    for (int i = 0; i < 32; i += 8)
        tile[ty + i][tx] = W[(size_t)(r0 + ty + i) * DMODEL + c0 + tx];
    __syncthreads();
#pragma unroll
    for (int i = 0; i < 32; i += 8)
        O[(size_t)(c0 + ty + i) * DMODEL + r0 + tx] = (bf16_t)tile[tx][ty + i];
}
__global__ __launch_bounds__(256) void cvt_bf16(
    const float* __restrict__ src, bf16_t* __restrict__ dst)
{
    size_t i = ((size_t)blockIdx.x * 256 + threadIdx.x) * 8;
    *(bf16x8*)(dst + i) = load_cvt8(src + i);
}

// ---------------- QKV projection GEMM, 128x128 tile, BK=32, dbuf single-barrier ----------------
__global__ __launch_bounds__(256) void gemm_qkv(
    const bf16_t* __restrict__ Xb, size_t astride, int mode0,
    const bf16_t* __restrict__ Wt,
    const float* __restrict__ bq, const float* __restrict__ bk, const float* __restrict__ bv,
    bf16_t* __restrict__ Qh, bf16_t* __restrict__ Kh, bf16_t* __restrict__ Vt)
{
    const int mode = mode0 + blockIdx.z;
    const bf16_t* A = Xb + astride * (size_t)blockIdx.z;
    const bf16_t* B = Wt + (size_t)mode * DMODEL * DMODEL;
    const float* bias = (mode == 0) ? bq : (mode == 1) ? bk : bv;
    bf16_t* out       = (mode == 0) ? Qh : (mode == 1) ? Kh : Vt;

    __shared__ __align__(16) bf16_t lA[2][128 * 32];
    __shared__ __align__(16) bf16_t lB[2][128 * 32];

    const int wave = threadIdx.x >> 6, lane = threadIdx.x & 63;
    const int quad = lane >> 4, l15 = lane & 15;
    const int wm = wave >> 1, wn = wave & 1;
    const int row0 = blockIdx.x * 128, col0 = blockIdx.y * 128;
    const int srow = lane >> 2, scol = (lane & 3) * 8;

    const floatx4 zero = {0.f, 0.f, 0.f, 0.f};
    floatx4 acc[4][4];
#pragma unroll
    for (int mt = 0; mt < 4; mt++)
#pragma unroll
        for (int nt = 0; nt < 4; nt++) acc[mt][nt] = zero;

#pragma unroll
    for (int j = 0; j < 2; j++) {
        const int seg = j * 4 + wave;
        gload16(A + (size_t)(row0 + seg * 16 + srow) * DMODEL + scol, lA[0] + seg * 512);
        gload16(B + (size_t)(col0 + seg * 16 + srow) * DMODEL + scol, lB[0] + seg * 512);
    }

    for (int it = 0; it < 32; it++) {
        __syncthreads();
        const int cur = it & 1;
        if (it + 1 < 32) {
            const int k1 = (it + 1) * 32;
            const int nb = cur ^ 1;
#pragma unroll
            for (int j = 0; j < 2; j++) {
                const int seg = j * 4 + wave;
                gload16(A + (size_t)(row0 + seg * 16 + srow) * DMODEL + k1 + scol, lA[nb] + seg * 512);
                gload16(B + (size_t)(col0 + seg * 16 + srow) * DMODEL + k1 + scol, lB[nb] + seg * 512);
            }
        }
        bf16x8 aF[4], bF[4];
#pragma unroll
        for (int t = 0; t < 4; t++) {
            aF[t] = *(const bf16x8*)(lA[cur] + (wm * 64 + t * 16 + l15) * 32 + quad * 8);
            bF[t] = *(const bf16x8*)(lB[cur] + (wn * 64 + t * 16 + l15) * 32 + quad * 8);
        }
#pragma unroll
        for (int mt = 0; mt < 4; mt++)
#pragma unroll
            for (int nt = 0; nt < 4; nt++)
                acc[mt][nt] = MFMA_BF16(aF[mt], bF[nt], acc[mt][nt]);
    }

#pragma unroll
    for (int nt = 0; nt < 4; nt++) {
        const int gn = col0 + wn * 64 + nt * 16 + l15;
        const float bb = bias[gn];
        const int hh = gn >> 6, dd = gn & 63;
#pragma unroll
        for (int mt = 0; mt < 4; mt++) {
#pragma unroll
            for (int r = 0; r < 4; r++) {
                const int tok = row0 + wm * 64 + mt * 16 + quad * 4 + r;
                const int b = tok >> 10, s = tok & 1023;
                float vv = acc[mt][nt][r] + bb;
                size_t addr;
                if (mode == 2) {
                    addr = ((size_t)((b * NHEAD + hh) * HDIM + dd)) * SEQLEN + s;
                } else {
                    if (mode == 0) vv *= 0.125f;  // 1/sqrt(Dk), exact pow2
                    addr = ((size_t)((b * NHEAD + hh) * SEQLEN + s)) * HDIM + dd;
                }
                out[addr] = (bf16_t)vv;
            }
        }
    }
}

// ---------------- output projection GEMM, 64x128 tile, dbuf single-barrier ----------------
__global__ __launch_bounds__(256) void gemm_o(
    const bf16_t* __restrict__ Xa, const bf16_t* __restrict__ Wt,
    const float* __restrict__ bias, float* __restrict__ out)
{
    __shared__ __align__(16) bf16_t lA[2][64 * 32];
    __shared__ __align__(16) bf16_t lB[2][128 * 32];

    const int wave = threadIdx.x >> 6, lane = threadIdx.x & 63;
    const int quad = lane >> 4, l15 = lane & 15;
    const int wm = wave & 1, wn = wave >> 1;
    const int row0 = blockIdx.x * 64, col0 = blockIdx.y * 128;
    const int srow = lane >> 2, scol = (lane & 3) * 8;

    const floatx4 zero = {0.f, 0.f, 0.f, 0.f};
    floatx4 acc[2][4];
#pragma unroll
    for (int mt = 0; mt < 2; mt++)
#pragma unroll
        for (int nt = 0; nt < 4; nt++) acc[mt][nt] = zero;

    gload16(Xa + (size_t)(row0 + wave * 16 + srow) * DMODEL + scol, lA[0] + wave * 512);
#pragma unroll
    for (int j = 0; j < 2; j++) {
        const int seg = wave * 2 + j;
        gload16(Wt + (size_t)(col0 + seg * 16 + srow) * DMODEL + scol, lB[0] + seg * 512);
    }

    for (int it = 0; it < 32; it++) {
        __syncthreads();
        const int cur = it & 1;
        if (it + 1 < 32) {
            const int k1 = (it + 1) * 32;
            const int nb = cur ^ 1;
            gload16(Xa + (size_t)(row0 + wave * 16 + srow) * DMODEL + k1 + scol, lA[nb] + wave * 512);
#pragma unroll
            for (int j = 0; j < 2; j++) {
                const int seg = wave * 2 + j;
                gload16(Wt + (size_t)(col0 + seg * 16 + srow) * DMODEL + k1 + scol, lB[nb] + seg * 512);
            }
        }
        bf16x8 aF[2], bF[4];
#pragma unroll
        for (int t = 0; t < 2; t++)
            aF[t] = *(const bf16x8*)(lA[cur] + (wm * 32 + t * 16 + l15) * 32 + quad * 8);
#pragma unroll
        for (int t = 0; t < 4; t++)
            bF[t] = *(const bf16x8*)(lB[cur] + (wn * 64 + t * 16 + l15) * 32 + quad * 8);
#pragma unroll
        for (int mt = 0; mt < 2; mt++)
#pragma unroll
            for (int nt = 0; nt < 4; nt++)
                acc[mt][nt] = MFMA_BF16(aF[mt], bF[nt], acc[mt][nt]);
    }

#pragma unroll
    for (int nt = 0; nt < 4; nt++) {
        const int gn = col0 + wn * 64 + nt * 16 + l15;
        const float bb = bias[gn];
#pragma unroll
        for (int mt = 0; mt < 2; mt++) {
#pragma unroll
            for (int r = 0; r < 4; r++) {
                const int tok = row0 + wm * 32 + mt * 16 + quad * 4 + r;
                out[(size_t)tok * DMODEL + gn] = acc[mt][nt][r] + bb;
            }
        }
    }
}

// ---------------- causal flash attention: K-split x4, pair-balanced, no online max ----------
// v4: one pair-tile per block, 4 waves split key-chunks by (kc mod 4); grid 2048 => 8
// blocks/CU x 4 waves = 32 waves/CU. launch_bounds kept at (256,4): v3's (256,8) capped
// the allocator at 64 VGPR and spilled ~675 MB/dispatch to scratch (VGPR_Count fell to 32,
// WRITE_SIZE 8 MB -> 411 MB, attn 157us). Actual need is 64 VGPR, which already permits
// 8 waves/SIMD -- occupancy comes from the grid, not the bound.
#define SOFTMAX_PV(S0x, S1x, qbase, qrow, lacc, oacc) do {                             \
    const bool nomask = (kb + 31 <= (qbase));                                          \
    float ps = 0.f;                                                                    \
    union { bf16_t hh2[8]; u32 u[4]; } pk;                                             \
    _Pragma("unroll") for (int r = 0; r < 4; r++) {                                    \
        const int key0 = kb + quad * 4 + r;                                            \
        float s0 = (nomask || key0 <= (qrow))      ? S0x[r] : -1e30f;                  \
        float s1 = (nomask || key0 + 16 <= (qrow)) ? S1x[r] : -1e30f;                  \
        float e0 = __expf(s0), e1 = __expf(s1);                                        \
        ps += e0 + e1;                                                                 \
        pk.hh2[r] = (bf16_t)e0; pk.hh2[4 + r] = (bf16_t)e1;                            \
    }                                                                                  \
    lacc += ps;                                                                        \
    u32 a0 = __shfl(pk.u[0], srcA), a1 = __shfl(pk.u[1], srcA);                        \
    u32 a2 = __shfl(pk.u[0], srcB), a3 = __shfl(pk.u[1], srcB);                        \
    u32 b0 = __shfl(pk.u[2], srcA), b1 = __shfl(pk.u[3], srcA);                        \
    u32 b2 = __shfl(pk.u[2], srcB), b3 = __shfl(pk.u[3], srcB);                        \
    union { u32 u[4]; bf16x8 v; } bP;                                                  \
    bP.u[0] = hiP ? b0 : a0; bP.u[1] = hiP ? b1 : a1;                                  \
    bP.u[2] = hiP ? b2 : a2; bP.u[3] = hiP ? b3 : a3;                                  \
    _Pragma("unroll") for (int dt = 0; dt < 4; dt++)                                   \
        oacc[dt] = MFMA_BF16(Vv[dt], bP.v, oacc[dt]);                                  \
} while (0)

__global__ __launch_bounds__(256, 4) void attn(
    const bf16_t* __restrict__ Qh, const bf16_t* __restrict__ Kh,
    const bf16_t* __restrict__ Vt, bf16_t* __restrict__ X)
{
    __shared__ __align__(8) float comb[2][64][34];     // partial publish: 32 o + 2 l
    const int wave = threadIdx.x >> 6, lane = threadIdx.x & 63;
    const int quad = lane >> 4, l15 = lane & 15;
    const int L = blockIdx.x;                          // [0,2048)
    const int bh = (L & 7) * 8 + ((L >> 3) & 7);       // 8 heads per XCD
    const int t  = L >> 6;                             // pair index [0,32)
    const int b = bh >> 4, h = bh & 15;

    const int qbaseA = 16 * t, qbaseB = 1008 - 16 * t;
    const int qrowA = qbaseA + l15, qrowB = qbaseB + l15;
    const int nkA = t / 2 + 1, nkB = 32 - t / 2;

    const bf16_t* Qp = Qh + (size_t)bh * SEQLEN * HDIM;
    const bf16_t* Kp = Kh + (size_t)bh * SEQLEN * HDIM;
    const bf16_t* Vp = Vt + (size_t)bh * HDIM * SEQLEN;

    bf16x8 bQA[2], bQB[2];
#pragma unroll
    for (int c = 0; c < 2; c++) {
        bQA[c] = *(const bf16x8*)(Qp + (size_t)qrowA * HDIM + c * 32 + quad * 8);
        bQB[c] = *(const bf16x8*)(Qp + (size_t)qrowB * HDIM + c * 32 + quad * 8);
    }

    const floatx4 zero = {0.f, 0.f, 0.f, 0.f};
    float lA_ = 0.f, lB_ = 0.f;
    floatx4 oA[4], oB[4];
#pragma unroll
    for (int dt = 0; dt < 4; dt++) { oA[dt] = zero; oB[dt] = zero; }

    const int srcA = ((quad & 1) ? 32 : 0) + l15;      // P-transpose shuffle sources
    const int srcB = srcA + 16;
    const bool hiP = (quad >= 2);

    for (int kc = wave; kc < nkB; kc += 4) {
        const int kb = kc * 32;
        bf16x8 K0[2], K1[2], Vv[4];
#pragma unroll
        for (int c = 0; c < 2; c++) {
            K0[c] = *(const bf16x8*)(Kp + (size_t)(kb + l15) * HDIM + c * 32 + quad * 8);
            K1[c] = *(const bf16x8*)(Kp + (size_t)(kb + 16 + l15) * HDIM + c * 32 + quad * 8);
        }
#pragma unroll
        for (int dt = 0; dt < 4; dt++)
            Vv[dt] = *(const bf16x8*)(Vp + (size_t)(dt * 16 + l15) * SEQLEN + kb + quad * 8);

        const bool doA = (kc < nkA);                   // wave-uniform
        floatx4 S0B = zero, S1B = zero, S0A = zero, S1A = zero;
#pragma unroll
        for (int c = 0; c < 2; c++) {
            S0B = MFMA_BF16(K0[c], bQB[c], S0B);
            S1B = MFMA_BF16(K1[c], bQB[c], S1B);
        }
        if (doA) {
#pragma unroll
            for (int c = 0; c < 2; c++) {
                S0A = MFMA_BF16(K0[c], bQA[c], S0A);
                S1A = MFMA_BF16(K1[c], bQA[c], S1A);
            }
        }
        SOFTMAX_PV(S0B, S1B, qbaseB, qrowB, lB_, oB);
        if (doA) { SOFTMAX_PV(S0A, S1A, qbaseA, qrowA, lA_, oA); }
    }

    // 2-stage partial combine through LDS: waves 1,3 -> 0,2; then wave 2 -> 0.
    auto publish = [&](int slot) {
        float2* d2 = (float2*)&comb[slot][lane][0];
#pragma unroll
        for (int dt = 0; dt < 4; dt++) {
            d2[2 * dt]     = make_float2(oA[dt][0], oA[dt][1]);
            d2[2 * dt + 1] = make_float2(oA[dt][2], oA[dt][3]);
            d2[8 + 2 * dt]     = make_float2(oB[dt][0], oB[dt][1]);
            d2[8 + 2 * dt + 1] = make_float2(oB[dt][2], oB[dt][3]);
        }
        d2[16] = make_float2(lA_, lB_);
    };
    auto accum = [&](int slot) {
        const float2* s2 = (const float2*)&comb[slot][lane][0];
#pragma unroll
        for (int dt = 0; dt < 4; dt++) {
            float2 x0 = s2[2 * dt], x1 = s2[2 * dt + 1];
            float2 y0 = s2[8 + 2 * dt], y1 = s2[8 + 2 * dt + 1];
            oA[dt][0] += x0.x; oA[dt][1] += x0.y; oA[dt][2] += x1.x; oA[dt][3] += x1.y;
            oB[dt][0] += y0.x; oB[dt][1] += y0.y; oB[dt][2] += y1.x; oB[dt][3] += y1.y;
        }
        float2 lp = s2[16];
        lA_ += lp.x; lB_ += lp.y;
    };

    if (wave & 1) publish(wave >> 1);                  // 1 -> slot 0, 3 -> slot 1
    __syncthreads();
    if (!(wave & 1)) accum(wave >> 1);                 // 0 += slot 0, 2 += slot 1
    __syncthreads();
    if (wave == 2) publish(0);
    __syncthreads();
    if (wave == 0) {
        accum(0);

        lA_ += __shfl_xor(lA_, 16); lA_ += __shfl_xor(lA_, 32);
        lB_ += __shfl_xor(lB_, 16); lB_ += __shfl_xor(lB_, 32);

        const float invA = 1.f / lA_, invB = 1.f / lB_;
#pragma unroll
        for (int dt = 0; dt < 4; dt++) {
            bf16x4 va, vb;
#pragma unroll
            for (int r = 0; r < 4; r++) {
                va[r] = (bf16_t)(oA[dt][r] * invA);
                vb[r] = (bf16_t)(oB[dt][r] * invB);
            }
            const size_t cofs = (size_t)h * HDIM + dt * 16 + quad * 4;
            *(bf16x4*)(&X[((size_t)(b * SEQLEN + qrowA)) * DMODEL + cofs]) = va;
            *(bf16x4*)(&X[((size_t)(b * SEQLEN + qrowB)) * DMODEL + cofs]) = vb;
        }
    }
}

extern "C" void kernel_launch(void* const* d_in, const int* in_sizes, int n_in,
                              void* d_out, int out_size, void* d_ws, size_t ws_size,
                              hipStream_t stream)
{
    const float* q  = (const float*)d_in[0];
    const float* k  = (const float*)d_in[1];
    const float* v  = (const float*)d_in[2];
    // d_in[3] = causal mask (deterministic tril) — applied analytically
    const float* Wq = (const float*)d_in[4];
    const float* bq = (const float*)d_in[5];
    const float* Wk = (const float*)d_in[6];
    const float* bk = (const float*)d_in[7];
    const float* Wv = (const float*)d_in[8];
    const float* bv = (const float*)d_in[9];
    const float* Wo = (const float*)d_in[10];
    const float* bo = (const float*)d_in[11];
    float* out = (float*)d_out;

    char* ws = (char*)d_ws;
    const size_t MB = 1ull << 20;
    const size_t NELEM = (size_t)NTOK * DMODEL;            // 4M elements / 8 MB bf16
    bf16_t* Wt = (bf16_t*)ws;                              // [0,8) MB
    bf16_t* Qh = (bf16_t*)(ws + 8 * MB);                   // [8,16)
    bf16_t* Kh = (bf16_t*)(ws + 16 * MB);                  // [16,24)
    bf16_t* Vt = (bf16_t*)(ws + 24 * MB);                  // [24,32)
    bf16_t* Xr = (bf16_t*)(ws + 32 * MB);                  // [32,...) staging; Xa overlays

    if (ws_size >= 56 * MB) {
        prep<<<dim3(32, 32, 7), dim3(256), 0, stream>>>(Wq, Wk, Wv, Wo, q, k, v, Wt, Xr);
        gemm_qkv<<<dim3(32, 8, 3), dim3(256), 0, stream>>>(
            Xr, NELEM, 0, Wt, bq, bk, bv, Qh, Kh, Vt);
    } else {
        transpose_w<<<dim3(32, 32, 4), dim3(32, 8), 0, stream>>>(Wq, Wk, Wv, Wo, Wt);
        const float* qkv_in[3] = {q, k, v};
        for (int m = 0; m < 3; m++) {
            cvt_bf16<<<dim3(2048), dim3(256), 0, stream>>>(qkv_in[m], Xr);
            gemm_qkv<<<dim3(32, 8, 1), dim3(256), 0, stream>>>(
                Xr, 0, m, Wt, bq, bk, bv, Qh, Kh, Vt);
        }
    }

    bf16_t* Xa = Xr;   // overlay q's bf16 copy (dead after gemm_qkv)
    attn<<<dim3(2048), dim3(256), 0, stream>>>(Qh, Kh, Vt, Xa);
    gemm_o<<<dim3(64, 8), dim3(256), 0, stream>>>(
        Xa, Wt + 3 * (size_t)DMODEL * DMODEL, bo, out);
}

// Round 4
// 237.402 us; speedup vs baseline: 1.4399x; 1.0026x over previous
//
#include <hip/hip_runtime.h>
#include <math.h>

typedef __bf16 bf16_t;
typedef bf16_t bf16x8 __attribute__((ext_vector_type(8)));
typedef bf16_t bf16x4 __attribute__((ext_vector_type(4)));
typedef float  floatx4 __attribute__((ext_vector_type(4)));
typedef unsigned int u32;

#define MFMA_BF16(a, b, c) __builtin_amdgcn_mfma_f32_16x16x32_bf16((a), (b), (c), 0, 0, 0)

#if __has_builtin(__builtin_amdgcn_exp2f)
#define EXP2F(x) __builtin_amdgcn_exp2f(x)
#else
#define EXP2F(x) exp2f(x)
#endif

static constexpr int DMODEL = 1024;
static constexpr int NHEAD  = 16;
static constexpr int HDIM   = 64;
static constexpr int NBATCH = 4;
static constexpr int SEQLEN = 1024;
static constexpr int NTOK   = NBATCH * SEQLEN;  // 4096

typedef __attribute__((address_space(3))) void       as3_void;
typedef __attribute__((address_space(1))) const void as1_cvoid;

// async global->LDS, 16B/lane; LDS dest = wave-uniform base + lane*16
__device__ __forceinline__ void gload16(const void* g, void* l) {
    __builtin_amdgcn_global_load_lds((as1_cvoid*)g, (as3_void*)l, 16, 0, 0);
}

// load 8 consecutive fp32, round to bf16x8
__device__ __forceinline__ bf16x8 load_cvt8(const float* __restrict__ p) {
    floatx4 a = *(const floatx4*)p;
    floatx4 b = *(const floatx4*)(p + 4);
    bf16x8 r;
    r[0] = (bf16_t)a[0]; r[1] = (bf16_t)a[1]; r[2] = (bf16_t)a[2]; r[3] = (bf16_t)a[3];
    r[4] = (bf16_t)b[0]; r[5] = (bf16_t)b[1]; r[6] = (bf16_t)b[2]; r[7] = (bf16_t)b[3];
    return r;
}

// ---------------- fused prep: z=0..3 transpose+cvt W_z; z=4..6 cvt q/k/v ----------------
__global__ __launch_bounds__(256) void prep(
    const float* __restrict__ W0, const float* __restrict__ W1,
    const float* __restrict__ W2, const float* __restrict__ W3,
    const float* __restrict__ q, const float* __restrict__ k, const float* __restrict__ v,
    bf16_t* __restrict__ Wt, bf16_t* __restrict__ Xr)
{
    __shared__ float tile[32][33];
    const int z = blockIdx.z;
    if (z < 4) {
        const float* W = (z == 0) ? W0 : (z == 1) ? W1 : (z == 2) ? W2 : W3;
        bf16_t* O = Wt + (size_t)z * DMODEL * DMODEL;
        const int tx = threadIdx.x & 31, ty = threadIdx.x >> 5;   // 32 x 8
        const int r0 = blockIdx.x * 32, c0 = blockIdx.y * 32;
#pragma unroll
        for (int i = 0; i < 32; i += 8)
            tile[ty + i][tx] = W[(size_t)(r0 + ty + i) * DMODEL + c0 + tx];
        __syncthreads();
#pragma unroll
        for (int i = 0; i < 32; i += 8)
            O[(size_t)(c0 + ty + i) * DMODEL + r0 + tx] = (bf16_t)tile[tx][ty + i];
    } else {
        const float* src = (z == 4) ? q : (z == 5) ? k : v;
        bf16_t* dst = Xr + (size_t)(z - 4) * ((size_t)NTOK * DMODEL);
        size_t i = (((size_t)blockIdx.y * 32 + blockIdx.x) * 256 + threadIdx.x) * 16;
        *(bf16x8*)(dst + i)     = load_cvt8(src + i);
        *(bf16x8*)(dst + i + 8) = load_cvt8(src + i + 8);
    }
}

// ---------------- fallback-path kernels (ws < 56 MB) ----------------
__global__ __launch_bounds__(256) void transpose_w(
    const float* __restrict__ W0, const float* __restrict__ W1,
    const float* __restrict__ W2, const float* __restrict__ W3,
    bf16_t* __restrict__ out)
{
    __shared__ float tile[32][33];
    const float* W = (blockIdx.z == 0) ? W0 : (blockIdx.z == 1) ? W1
                   : (blockIdx.z == 2) ? W2 : W3;
    bf16_t* O = out + (size_t)blockIdx.z * DMODEL * DMODEL;
    int tx = threadIdx.x, ty = threadIdx.y;           // 32 x 8
    int r0 = blockIdx.x * 32, c0 = blockIdx.y * 32;
#pragma unroll
    for (int i = 0; i < 32; i += 8)
        tile[ty + i][tx] = W[(size_t)(r0 + ty + i) * DMODEL + c0 + tx];
    __syncthreads();
#pragma unroll
    for (int i = 0; i < 32; i += 8)
        O[(size_t)(c0 + ty + i) * DMODEL + r0 + tx] = (bf16_t)tile[tx][ty + i];
}
__global__ __launch_bounds__(256) void cvt_bf16(
    const float* __restrict__ src, bf16_t* __restrict__ dst)
{
    size_t i = ((size_t)blockIdx.x * 256 + threadIdx.x) * 8;
    *(bf16x8*)(dst + i) = load_cvt8(src + i);
}

// ---------------- QKV projection GEMM, 128x128 tile, BK=32, dbuf single-barrier ----------------
__global__ __launch_bounds__(256) void gemm_qkv(
    const bf16_t* __restrict__ Xb, size_t astride, int mode0,
    const bf16_t* __restrict__ Wt,
    const float* __restrict__ bq, const float* __restrict__ bk, const float* __restrict__ bv,
    bf16_t* __restrict__ Qh, bf16_t* __restrict__ Kh, bf16_t* __restrict__ Vt)
{
    const int mode = mode0 + blockIdx.z;
    const bf16_t* A = Xb + astride * (size_t)blockIdx.z;
    const bf16_t* B = Wt + (size_t)mode * DMODEL * DMODEL;
    const float* bias = (mode == 0) ? bq : (mode == 1) ? bk : bv;
    bf16_t* out       = (mode == 0) ? Qh : (mode == 1) ? Kh : Vt;

    __shared__ __align__(16) bf16_t lA[2][128 * 32];
    __shared__ __align__(16) bf16_t lB[2][128 * 32];

    const int wave = threadIdx.x >> 6, lane = threadIdx.x & 63;
    const int quad = lane >> 4, l15 = lane & 15;
    const int wm = wave >> 1, wn = wave & 1;
    const int row0 = blockIdx.x * 128, col0 = blockIdx.y * 128;
    const int srow = lane >> 2, scol = (lane & 3) * 8;

    const floatx4 zero = {0.f, 0.f, 0.f, 0.f};
    floatx4 acc[4][4];
#pragma unroll
    for (int mt = 0; mt < 4; mt++)
#pragma unroll
        for (int nt = 0; nt < 4; nt++) acc[mt][nt] = zero;

#pragma unroll
    for (int j = 0; j < 2; j++) {
        const int seg = j * 4 + wave;
        gload16(A + (size_t)(row0 + seg * 16 + srow) * DMODEL + scol, lA[0] + seg * 512);
        gload16(B + (size_t)(col0 + seg * 16 + srow) * DMODEL + scol, lB[0] + seg * 512);
    }

    for (int it = 0; it < 32; it++) {
        __syncthreads();
        const int cur = it & 1;
        if (it + 1 < 32) {
            const int k1 = (it + 1) * 32;
            const int nb = cur ^ 1;
#pragma unroll
            for (int j = 0; j < 2; j++) {
                const int seg = j * 4 + wave;
                gload16(A + (size_t)(row0 + seg * 16 + srow) * DMODEL + k1 + scol, lA[nb] + seg * 512);
                gload16(B + (size_t)(col0 + seg * 16 + srow) * DMODEL + k1 + scol, lB[nb] + seg * 512);
            }
        }
        bf16x8 aF[4], bF[4];
#pragma unroll
        for (int t = 0; t < 4; t++) {
            aF[t] = *(const bf16x8*)(lA[cur] + (wm * 64 + t * 16 + l15) * 32 + quad * 8);
            bF[t] = *(const bf16x8*)(lB[cur] + (wn * 64 + t * 16 + l15) * 32 + quad * 8);
        }
#pragma unroll
        for (int mt = 0; mt < 4; mt++)
#pragma unroll
            for (int nt = 0; nt < 4; nt++)
                acc[mt][nt] = MFMA_BF16(aF[mt], bF[nt], acc[mt][nt]);
    }

#pragma unroll
    for (int nt = 0; nt < 4; nt++) {
        const int gn = col0 + wn * 64 + nt * 16 + l15;
        const float bb = bias[gn];
        const int hh = gn >> 6, dd = gn & 63;
#pragma unroll
        for (int mt = 0; mt < 4; mt++) {
#pragma unroll
            for (int r = 0; r < 4; r++) {
                const int tok = row0 + wm * 64 + mt * 16 + quad * 4 + r;
                const int b = tok >> 10, s = tok & 1023;
                float vv = acc[mt][nt][r] + bb;
                size_t addr;
                if (mode == 2) {
                    addr = ((size_t)((b * NHEAD + hh) * HDIM + dd)) * SEQLEN + s;
                } else {
                    // Q: fold 1/sqrt(Dk) AND log2(e) so softmax uses raw exp2
                    if (mode == 0) vv *= 0.1803368801111204f;
                    addr = ((size_t)((b * NHEAD + hh) * SEQLEN + s)) * HDIM + dd;
                }
                out[addr] = (bf16_t)vv;
            }
        }
    }
}

// ---------------- output projection GEMM, 64x128 tile, dbuf single-barrier ----------------
__global__ __launch_bounds__(256) void gemm_o(
    const bf16_t* __restrict__ Xa, const bf16_t* __restrict__ Wt,
    const float* __restrict__ bias, float* __restrict__ out)
{
    __shared__ __align__(16) bf16_t lA[2][64 * 32];
    __shared__ __align__(16) bf16_t lB[2][128 * 32];

    const int wave = threadIdx.x >> 6, lane = threadIdx.x & 63;
    const int quad = lane >> 4, l15 = lane & 15;
    const int wm = wave & 1, wn = wave >> 1;
    const int row0 = blockIdx.x * 64, col0 = blockIdx.y * 128;
    const int srow = lane >> 2, scol = (lane & 3) * 8;

    const floatx4 zero = {0.f, 0.f, 0.f, 0.f};
    floatx4 acc[2][4];
#pragma unroll
    for (int mt = 0; mt < 2; mt++)
#pragma unroll
        for (int nt = 0; nt < 4; nt++) acc[mt][nt] = zero;

    gload16(Xa + (size_t)(row0 + wave * 16 + srow) * DMODEL + scol, lA[0] + wave * 512);
#pragma unroll
    for (int j = 0; j < 2; j++) {
        const int seg = wave * 2 + j;
        gload16(Wt + (size_t)(col0 + seg * 16 + srow) * DMODEL + scol, lB[0] + seg * 512);
    }

    for (int it = 0; it < 32; it++) {
        __syncthreads();
        const int cur = it & 1;
        if (it + 1 < 32) {
            const int k1 = (it + 1) * 32;
            const int nb = cur ^ 1;
            gload16(Xa + (size_t)(row0 + wave * 16 + srow) * DMODEL + k1 + scol, lA[nb] + wave * 512);
#pragma unroll
            for (int j = 0; j < 2; j++) {
                const int seg = wave * 2 + j;
                gload16(Wt + (size_t)(col0 + seg * 16 + srow) * DMODEL + k1 + scol, lB[nb] + seg * 512);
            }
        }
        bf16x8 aF[2], bF[4];
#pragma unroll
        for (int t = 0; t < 2; t++)
            aF[t] = *(const bf16x8*)(lA[cur] + (wm * 32 + t * 16 + l15) * 32 + quad * 8);
#pragma unroll
        for (int t = 0; t < 4; t++)
            bF[t] = *(const bf16x8*)(lB[cur] + (wn * 64 + t * 16 + l15) * 32 + quad * 8);
#pragma unroll
        for (int mt = 0; mt < 2; mt++)
#pragma unroll
            for (int nt = 0; nt < 4; nt++)
                acc[mt][nt] = MFMA_BF16(aF[mt], bF[nt], acc[mt][nt]);
    }

#pragma unroll
    for (int nt = 0; nt < 4; nt++) {
        const int gn = col0 + wn * 64 + nt * 16 + l15;
        const float bb = bias[gn];
#pragma unroll
        for (int mt = 0; mt < 2; mt++) {
#pragma unroll
            for (int r = 0; r < 4; r++) {
                const int tok = row0 + wm * 32 + mt * 16 + quad * 4 + r;
                out[(size_t)tok * DMODEL + gn] = acc[mt][nt][r] + bb;
            }
        }
    }
}

// ---------------- causal flash attention: K-split x4, pair-balanced, no online max ----------
// v5: (a) launch_bounds(256,2): R3 proved residency beyond ~4 blocks/CU is worthless
// (grid 2x -> dur identical), so trade wave slots for registers; (b) explicit 2x-unrolled
// K+V prefetch into two NAMED register sets (no rotation copies -> compiler can't sink;
// sched_barrier(0) pins the load groups) => steady-state counted vmcnt, next tile in
// flight; (c) wave-uniform mask branch: FAST path (no per-element cmp/sel, bare v_exp)
// for the ~46/48 unmasked chunks; log2(e) folded into Q scale; (d) s_setprio around MFMA.
#define SHUF_PV(pk, Vv, oacc) do {                                                     \
    u32 a0 = __shfl(pk.u[0], srcA), a1 = __shfl(pk.u[1], srcA);                        \
    u32 a2 = __shfl(pk.u[0], srcB), a3 = __shfl(pk.u[1], srcB);                        \
    u32 b0 = __shfl(pk.u[2], srcA), b1 = __shfl(pk.u[3], srcA);                        \
    u32 b2 = __shfl(pk.u[2], srcB), b3 = __shfl(pk.u[3], srcB);                        \
    union { u32 u[4]; bf16x8 v; } bP;                                                  \
    bP.u[0] = hiP ? b0 : a0; bP.u[1] = hiP ? b1 : a1;                                  \
    bP.u[2] = hiP ? b2 : a2; bP.u[3] = hiP ? b3 : a3;                                  \
    __builtin_amdgcn_s_setprio(1);                                                     \
    _Pragma("unroll") for (int dt = 0; dt < 4; dt++)                                   \
        oacc[dt] = MFMA_BF16(Vv[dt], bP.v, oacc[dt]);                                  \
    __builtin_amdgcn_s_setprio(0);                                                     \
} while (0)

#define SOFTMAX_PV_FAST(S0x, S1x, Vv, lacc, oacc) do {                                 \
    float ps = 0.f;                                                                    \
    union { bf16_t hh2[8]; u32 u[4]; } pk;                                             \
    _Pragma("unroll") for (int r = 0; r < 4; r++) {                                    \
        float e0 = EXP2F(S0x[r]), e1 = EXP2F(S1x[r]);                                  \
        ps += e0 + e1;                                                                 \
        pk.hh2[r] = (bf16_t)e0; pk.hh2[4 + r] = (bf16_t)e1;                            \
    }                                                                                  \
    lacc += ps;                                                                        \
    SHUF_PV(pk, Vv, oacc);                                                             \
} while (0)

#define SOFTMAX_PV_MASK(S0x, S1x, Vv, kbv, qrow, lacc, oacc) do {                      \
    float ps = 0.f;                                                                    \
    union { bf16_t hh2[8]; u32 u[4]; } pk;                                             \
    _Pragma("unroll") for (int r = 0; r < 4; r++) {                                    \
        const int key0 = (kbv) + quad * 4 + r;                                         \
        float s0 = (key0 <= (qrow))      ? S0x[r] : -1e30f;                            \
        float s1 = (key0 + 16 <= (qrow)) ? S1x[r] : -1e30f;                            \
        float e0 = EXP2F(s0), e1 = EXP2F(s1);                                          \
        ps += e0 + e1;                                                                 \
        pk.hh2[r] = (bf16_t)e0; pk.hh2[4 + r] = (bf16_t)e1;                            \
    }                                                                                  \
    lacc += ps;                                                                        \
    SHUF_PV(pk, Vv, oacc);                                                             \
} while (0)

#define LOAD_KV(K0v, K1v, Vv, kbv) do {                                                \
    _Pragma("unroll") for (int c = 0; c < 2; c++) {                                    \
        K0v[c] = *(const bf16x8*)(Kp + (size_t)((kbv) + l15) * HDIM + c * 32 + quad * 8);      \
        K1v[c] = *(const bf16x8*)(Kp + (size_t)((kbv) + 16 + l15) * HDIM + c * 32 + quad * 8); \
    }                                                                                  \
    _Pragma("unroll") for (int dt = 0; dt < 4; dt++)                                   \
        Vv[dt] = *(const bf16x8*)(Vp + (size_t)(dt * 16 + l15) * SEQLEN + (kbv) + quad * 8);   \
} while (0)

#define COMPUTE(K0v, K1v, Vv, kcv) do {                                                \
    const int kb_ = (kcv) * 32;                                                        \
    const bool doA_ = (kcv) < nkA;                                                     \
    floatx4 S0B = zero, S1B = zero, S0A = zero, S1A = zero;                            \
    __builtin_amdgcn_s_setprio(1);                                                     \
    _Pragma("unroll") for (int c = 0; c < 2; c++) {                                    \
        S0B = MFMA_BF16(K0v[c], bQB[c], S0B);                                          \
        S1B = MFMA_BF16(K1v[c], bQB[c], S1B);                                          \
    }                                                                                  \
    __builtin_amdgcn_s_setprio(0);                                                     \
    if (doA_) {                                                                        \
        __builtin_amdgcn_s_setprio(1);                                                 \
        _Pragma("unroll") for (int c = 0; c < 2; c++) {                                \
            S0A = MFMA_BF16(K0v[c], bQA[c], S0A);                                      \
            S1A = MFMA_BF16(K1v[c], bQA[c], S1A);                                      \
        }                                                                              \
        __builtin_amdgcn_s_setprio(0);                                                 \
    }                                                                                  \
    if (kb_ + 31 <= qbaseB) { SOFTMAX_PV_FAST(S0B, S1B, Vv, lB_, oB); }                \
    else                    { SOFTMAX_PV_MASK(S0B, S1B, Vv, kb_, qrowB, lB_, oB); }    \
    if (doA_) {                                                                        \
        if (kb_ + 31 <= qbaseA) { SOFTMAX_PV_FAST(S0A, S1A, Vv, lA_, oA); }            \
        else                    { SOFTMAX_PV_MASK(S0A, S1A, Vv, kb_, qrowA, lA_, oA); }\
    }                                                                                  \
} while (0)

__global__ __launch_bounds__(256, 2) void attn(
    const bf16_t* __restrict__ Qh, const bf16_t* __restrict__ Kh,
    const bf16_t* __restrict__ Vt, bf16_t* __restrict__ X)
{
    __shared__ __align__(8) float comb[2][64][34];     // partial publish: 32 o + 2 l
    const int wave = threadIdx.x >> 6, lane = threadIdx.x & 63;
    const int quad = lane >> 4, l15 = lane & 15;
    const int L = blockIdx.x;                          // [0,2048)
    const int bh = (L & 7) * 8 + ((L >> 3) & 7);       // 8 heads per XCD
    const int t  = L >> 6;                             // pair index [0,32)
    const int b = bh >> 4, h = bh & 15;

    const int qbaseA = 16 * t, qbaseB = 1008 - 16 * t;
    const int qrowA = qbaseA + l15, qrowB = qbaseB + l15;
    const int nkA = t / 2 + 1, nkB = 32 - t / 2;

    const bf16_t* Qp = Qh + (size_t)bh * SEQLEN * HDIM;
    const bf16_t* Kp = Kh + (size_t)bh * SEQLEN * HDIM;
    const bf16_t* Vp = Vt + (size_t)bh * HDIM * SEQLEN;

    bf16x8 bQA[2], bQB[2];
#pragma unroll
    for (int c = 0; c < 2; c++) {
        bQA[c] = *(const bf16x8*)(Qp + (size_t)qrowA * HDIM + c * 32 + quad * 8);
        bQB[c] = *(const bf16x8*)(Qp + (size_t)qrowB * HDIM + c * 32 + quad * 8);
    }

    const floatx4 zero = {0.f, 0.f, 0.f, 0.f};
    float lA_ = 0.f, lB_ = 0.f;
    floatx4 oA[4], oB[4];
#pragma unroll
    for (int dt = 0; dt < 4; dt++) { oA[dt] = zero; oB[dt] = zero; }

    const int srcA = ((quad & 1) ? 32 : 0) + l15;      // P-transpose shuffle sources
    const int srcB = srcA + 16;
    const bool hiP = (quad >= 2);

    // ---- 2x-unrolled software pipeline with named register sets X/Y ----
    bf16x8 K0x[2], K1x[2], Vx[4];
    bf16x8 K0y[2], K1y[2], Vy[4];
    int kc = wave;                                     // nkB >= 17 > wave, always valid
    LOAD_KV(K0x, K1x, Vx, kc * 32);
    __builtin_amdgcn_sched_barrier(0);
    for (; kc + 4 < nkB; kc += 8) {
        LOAD_KV(K0y, K1y, Vy, (kc + 4) * 32);
        __builtin_amdgcn_sched_barrier(0);
        COMPUTE(K0x, K1x, Vx, kc);
        if (kc + 8 < nkB) {
            LOAD_KV(K0x, K1x, Vx, (kc + 8) * 32);
            __builtin_amdgcn_sched_barrier(0);
        }
        COMPUTE(K0y, K1y, Vy, kc + 4);
    }
    if (kc < nkB) COMPUTE(K0x, K1x, Vx, kc);

    // 2-stage partial combine through LDS: waves 1,3 -> 0,2; then wave 2 -> 0.
    auto publish = [&](int slot) {
        float2* d2 = (float2*)&comb[slot][lane][0];
#pragma unroll
        for (int dt = 0; dt < 4; dt++) {
            d2[2 * dt]     = make_float2(oA[dt][0], oA[dt][1]);
            d2[2 * dt + 1] = make_float2(oA[dt][2], oA[dt][3]);
            d2[8 + 2 * dt]     = make_float2(oB[dt][0], oB[dt][1]);
            d2[8 + 2 * dt + 1] = make_float2(oB[dt][2], oB[dt][3]);
        }
        d2[16] = make_float2(lA_, lB_);
    };
    auto accum = [&](int slot) {
        const float2* s2 = (const float2*)&comb[slot][lane][0];
#pragma unroll
        for (int dt = 0; dt < 4; dt++) {
            float2 x0 = s2[2 * dt], x1 = s2[2 * dt + 1];
            float2 y0 = s2[8 + 2 * dt], y1 = s2[8 + 2 * dt + 1];
            oA[dt][0] += x0.x; oA[dt][1] += x0.y; oA[dt][2] += x1.x; oA[dt][3] += x1.y;
            oB[dt][0] += y0.x; oB[dt][1] += y0.y; oB[dt][2] += y1.x; oB[dt][3] += y1.y;
        }
        float2 lp = s2[16];
        lA_ += lp.x; lB_ += lp.y;
    };

    if (wave & 1) publish(wave >> 1);                  // 1 -> slot 0, 3 -> slot 1
    __syncthreads();
    if (!(wave & 1)) accum(wave >> 1);                 // 0 += slot 0, 2 += slot 1
    __syncthreads();
    if (wave == 2) publish(0);
    __syncthreads();
    if (wave == 0) {
        accum(0);

        lA_ += __shfl_xor(lA_, 16); lA_ += __shfl_xor(lA_, 32);
        lB_ += __shfl_xor(lB_, 16); lB_ += __shfl_xor(lB_, 32);

        const float invA = 1.f / lA_, invB = 1.f / lB_;
#pragma unroll
        for (int dt = 0; dt < 4; dt++) {
            bf16x4 va, vb;
#pragma unroll
            for (int r = 0; r < 4; r++) {
                va[r] = (bf16_t)(oA[dt][r] * invA);
                vb[r] = (bf16_t)(oB[dt][r] * invB);
            }
            const size_t cofs = (size_t)h * HDIM + dt * 16 + quad * 4;
            *(bf16x4*)(&X[((size_t)(b * SEQLEN + qrowA)) * DMODEL + cofs]) = va;
            *(bf16x4*)(&X[((size_t)(b * SEQLEN + qrowB)) * DMODEL + cofs]) = vb;
        }
    }
}

extern "C" void kernel_launch(void* const* d_in, const int* in_sizes, int n_in,
                              void* d_out, int out_size, void* d_ws, size_t ws_size,
                              hipStream_t stream)
{
    const float* q  = (const float*)d_in[0];
    const float* k  = (const float*)d_in[1];
    const float* v  = (const float*)d_in[2];
    // d_in[3] = causal mask (deterministic tril) — applied analytically
    const float* Wq = (const float*)d_in[4];
    const float* bq = (const float*)d_in[5];
    const float* Wk = (const float*)d_in[6];
    const float* bk = (const float*)d_in[7];
    const float* Wv = (const float*)d_in[8];
    const float* bv = (const float*)d_in[9];
    const float* Wo = (const float*)d_in[10];
    const float* bo = (const float*)d_in[11];
    float* out = (float*)d_out;

    char* ws = (char*)d_ws;
    const size_t MB = 1ull << 20;
    const size_t NELEM = (size_t)NTOK * DMODEL;            // 4M elements / 8 MB bf16
    bf16_t* Wt = (bf16_t*)ws;                              // [0,8) MB
    bf16_t* Qh = (bf16_t*)(ws + 8 * MB);                   // [8,16)
    bf16_t* Kh = (bf16_t*)(ws + 16 * MB);                  // [16,24)
    bf16_t* Vt = (bf16_t*)(ws + 24 * MB);                  // [24,32)
    bf16_t* Xr = (bf16_t*)(ws + 32 * MB);                  // [32,...) staging; Xa overlays

    if (ws_size >= 56 * MB) {
        prep<<<dim3(32, 32, 7), dim3(256), 0, stream>>>(Wq, Wk, Wv, Wo, q, k, v, Wt, Xr);
        gemm_qkv<<<dim3(32, 8, 3), dim3(256), 0, stream>>>(
            Xr, NELEM, 0, Wt, bq, bk, bv, Qh, Kh, Vt);
    } else {
        transpose_w<<<dim3(32, 32, 4), dim3(32, 8), 0, stream>>>(Wq, Wk, Wv, Wo, Wt);
        const float* qkv_in[3] = {q, k, v};
        for (int m = 0; m < 3; m++) {
            cvt_bf16<<<dim3(2048), dim3(256), 0, stream>>>(qkv_in[m], Xr);
            gemm_qkv<<<dim3(32, 8, 1), dim3(256), 0, stream>>>(
                Xr, 0, m, Wt, bq, bk, bv, Qh, Kh, Vt);
        }
    }

    bf16_t* Xa = Xr;   // overlay q's bf16 copy (dead after gemm_qkv)
    attn<<<dim3(2048), dim3(256), 0, stream>>>(Qh, Kh, Vt, Xa);
    gemm_o<<<dim3(64, 8), dim3(256), 0, stream>>>(
        Xa, Wt + 3 * (size_t)DMODEL * DMODEL, bo, out);
}

// Round 5
// 219.938 us; speedup vs baseline: 1.5542x; 1.0794x over previous
//
#include <hip/hip_runtime.h>
#include <math.h>

typedef __bf16 bf16_t;
typedef bf16_t bf16x8 __attribute__((ext_vector_type(8)));
typedef bf16_t bf16x4 __attribute__((ext_vector_type(4)));
typedef float  floatx4 __attribute__((ext_vector_type(4)));
typedef unsigned int u32;

#define MFMA_BF16(a, b, c) __builtin_amdgcn_mfma_f32_16x16x32_bf16((a), (b), (c), 0, 0, 0)

#if __has_builtin(__builtin_amdgcn_exp2f)
#define EXP2F(x) __builtin_amdgcn_exp2f(x)
#else
#define EXP2F(x) exp2f(x)
#endif

static constexpr int DMODEL = 1024;
static constexpr int NHEAD  = 16;
static constexpr int HDIM   = 64;
static constexpr int NBATCH = 4;
static constexpr int SEQLEN = 1024;
static constexpr int NTOK   = NBATCH * SEQLEN;  // 4096

typedef __attribute__((address_space(3))) void       as3_void;
typedef __attribute__((address_space(1))) const void as1_cvoid;

// async global->LDS, 16B/lane; LDS dest = wave-uniform base + lane*16
__device__ __forceinline__ void gload16(const void* g, void* l) {
    __builtin_amdgcn_global_load_lds((as1_cvoid*)g, (as3_void*)l, 16, 0, 0);
}

// load 8 consecutive fp32, round to bf16x8
__device__ __forceinline__ bf16x8 load_cvt8(const float* __restrict__ p) {
    floatx4 a = *(const floatx4*)p;
    floatx4 b = *(const floatx4*)(p + 4);
    bf16x8 r;
    r[0] = (bf16_t)a[0]; r[1] = (bf16_t)a[1]; r[2] = (bf16_t)a[2]; r[3] = (bf16_t)a[3];
    r[4] = (bf16_t)b[0]; r[5] = (bf16_t)b[1]; r[6] = (bf16_t)b[2]; r[7] = (bf16_t)b[3];
    return r;
}

// ---------------- fused prep: z=0..3 transpose+cvt W_z; z=4..6 cvt q/k/v ----------------
__global__ __launch_bounds__(256) void prep(
    const float* __restrict__ W0, const float* __restrict__ W1,
    const float* __restrict__ W2, const float* __restrict__ W3,
    const float* __restrict__ q, const float* __restrict__ k, const float* __restrict__ v,
    bf16_t* __restrict__ Wt, bf16_t* __restrict__ Xr)
{
    __shared__ float tile[32][33];
    const int z = blockIdx.z;
    if (z < 4) {
        const float* W = (z == 0) ? W0 : (z == 1) ? W1 : (z == 2) ? W2 : W3;
        bf16_t* O = Wt + (size_t)z * DMODEL * DMODEL;
        const int tx = threadIdx.x & 31, ty = threadIdx.x >> 5;   // 32 x 8
        const int r0 = blockIdx.x * 32, c0 = blockIdx.y * 32;
#pragma unroll
        for (int i = 0; i < 32; i += 8)
            tile[ty + i][tx] = W[(size_t)(r0 + ty + i) * DMODEL + c0 + tx];
        __syncthreads();
#pragma unroll
        for (int i = 0; i < 32; i += 8)
            O[(size_t)(c0 + ty + i) * DMODEL + r0 + tx] = (bf16_t)tile[tx][ty + i];
    } else {
        const float* src = (z == 4) ? q : (z == 5) ? k : v;
        bf16_t* dst = Xr + (size_t)(z - 4) * ((size_t)NTOK * DMODEL);
        size_t i = (((size_t)blockIdx.y * 32 + blockIdx.x) * 256 + threadIdx.x) * 16;
        *(bf16x8*)(dst + i)     = load_cvt8(src + i);
        *(bf16x8*)(dst + i + 8) = load_cvt8(src + i + 8);
    }
}

// ---------------- fallback-path kernels (ws < 56 MB) ----------------
__global__ __launch_bounds__(256) void transpose_w(
    const float* __restrict__ W0, const float* __restrict__ W1,
    const float* __restrict__ W2, const float* __restrict__ W3,
    bf16_t* __restrict__ out)
{
    __shared__ float tile[32][33];
    const float* W = (blockIdx.z == 0) ? W0 : (blockIdx.z == 1) ? W1
                   : (blockIdx.z == 2) ? W2 : W3;
    bf16_t* O = out + (size_t)blockIdx.z * DMODEL * DMODEL;
    int tx = threadIdx.x, ty = threadIdx.y;           // 32 x 8
    int r0 = blockIdx.x * 32, c0 = blockIdx.y * 32;
#pragma unroll
    for (int i = 0; i < 32; i += 8)
        tile[ty + i][tx] = W[(size_t)(r0 + ty + i) * DMODEL + c0 + tx];
    __syncthreads();
#pragma unroll
    for (int i = 0; i < 32; i += 8)
        O[(size_t)(c0 + ty + i) * DMODEL + r0 + tx] = (bf16_t)tile[tx][ty + i];
}
__global__ __launch_bounds__(256) void cvt_bf16(
    const float* __restrict__ src, bf16_t* __restrict__ dst)
{
    size_t i = ((size_t)blockIdx.x * 256 + threadIdx.x) * 8;
    *(bf16x8*)(dst + i) = load_cvt8(src + i);
}

// ---------------- QKV projection GEMM, 128x128 tile, BK=32, dbuf single-barrier ----------------
__global__ __launch_bounds__(256) void gemm_qkv(
    const bf16_t* __restrict__ Xb, size_t astride, int mode0,
    const bf16_t* __restrict__ Wt,
    const float* __restrict__ bq, const float* __restrict__ bk, const float* __restrict__ bv,
    bf16_t* __restrict__ Qh, bf16_t* __restrict__ Kh, bf16_t* __restrict__ Vt)
{
    const int mode = mode0 + blockIdx.z;
    const bf16_t* A = Xb + astride * (size_t)blockIdx.z;
    const bf16_t* B = Wt + (size_t)mode * DMODEL * DMODEL;
    const float* bias = (mode == 0) ? bq : (mode == 1) ? bk : bv;
    bf16_t* out       = (mode == 0) ? Qh : (mode == 1) ? Kh : Vt;

    __shared__ __align__(16) bf16_t lA[2][128 * 32];
    __shared__ __align__(16) bf16_t lB[2][128 * 32];

    const int wave = threadIdx.x >> 6, lane = threadIdx.x & 63;
    const int quad = lane >> 4, l15 = lane & 15;
    const int wm = wave >> 1, wn = wave & 1;
    const int row0 = blockIdx.x * 128, col0 = blockIdx.y * 128;
    const int srow = lane >> 2, scol = (lane & 3) * 8;

    const floatx4 zero = {0.f, 0.f, 0.f, 0.f};
    floatx4 acc[4][4];
#pragma unroll
    for (int mt = 0; mt < 4; mt++)
#pragma unroll
        for (int nt = 0; nt < 4; nt++) acc[mt][nt] = zero;

#pragma unroll
    for (int j = 0; j < 2; j++) {
        const int seg = j * 4 + wave;
        gload16(A + (size_t)(row0 + seg * 16 + srow) * DMODEL + scol, lA[0] + seg * 512);
        gload16(B + (size_t)(col0 + seg * 16 + srow) * DMODEL + scol, lB[0] + seg * 512);
    }

    for (int it = 0; it < 32; it++) {
        __syncthreads();
        const int cur = it & 1;
        if (it + 1 < 32) {
            const int k1 = (it + 1) * 32;
            const int nb = cur ^ 1;
#pragma unroll
            for (int j = 0; j < 2; j++) {
                const int seg = j * 4 + wave;
                gload16(A + (size_t)(row0 + seg * 16 + srow) * DMODEL + k1 + scol, lA[nb] + seg * 512);
                gload16(B + (size_t)(col0 + seg * 16 + srow) * DMODEL + k1 + scol, lB[nb] + seg * 512);
            }
        }
        bf16x8 aF[4], bF[4];
#pragma unroll
        for (int t = 0; t < 4; t++) {
            aF[t] = *(const bf16x8*)(lA[cur] + (wm * 64 + t * 16 + l15) * 32 + quad * 8);
            bF[t] = *(const bf16x8*)(lB[cur] + (wn * 64 + t * 16 + l15) * 32 + quad * 8);
        }
#pragma unroll
        for (int mt = 0; mt < 4; mt++)
#pragma unroll
            for (int nt = 0; nt < 4; nt++)
                acc[mt][nt] = MFMA_BF16(aF[mt], bF[nt], acc[mt][nt]);
    }

#pragma unroll
    for (int nt = 0; nt < 4; nt++) {
        const int gn = col0 + wn * 64 + nt * 16 + l15;
        const float bb = bias[gn];
        const int hh = gn >> 6, dd = gn & 63;
#pragma unroll
        for (int mt = 0; mt < 4; mt++) {
#pragma unroll
            for (int r = 0; r < 4; r++) {
                const int tok = row0 + wm * 64 + mt * 16 + quad * 4 + r;
                const int b = tok >> 10, s = tok & 1023;
                float vv = acc[mt][nt][r] + bb;
                size_t addr;
                if (mode == 2) {
                    addr = ((size_t)((b * NHEAD + hh) * HDIM + dd)) * SEQLEN + s;
                } else {
                    // Q: fold 1/sqrt(Dk) AND log2(e) so softmax uses raw exp2
                    if (mode == 0) vv *= 0.1803368801111204f;
                    addr = ((size_t)((b * NHEAD + hh) * SEQLEN + s)) * HDIM + dd;
                }
                out[addr] = (bf16_t)vv;
            }
        }
    }
}

// ---------------- output projection GEMM, 64x128 tile, dbuf single-barrier ----------------
__global__ __launch_bounds__(256) void gemm_o(
    const bf16_t* __restrict__ Xa, const bf16_t* __restrict__ Wt,
    const float* __restrict__ bias, float* __restrict__ out)
{
    __shared__ __align__(16) bf16_t lA[2][64 * 32];
    __shared__ __align__(16) bf16_t lB[2][128 * 32];

    const int wave = threadIdx.x >> 6, lane = threadIdx.x & 63;
    const int quad = lane >> 4, l15 = lane & 15;
    const int wm = wave & 1, wn = wave >> 1;
    const int row0 = blockIdx.x * 64, col0 = blockIdx.y * 128;
    const int srow = lane >> 2, scol = (lane & 3) * 8;

    const floatx4 zero = {0.f, 0.f, 0.f, 0.f};
    floatx4 acc[2][4];
#pragma unroll
    for (int mt = 0; mt < 2; mt++)
#pragma unroll
        for (int nt = 0; nt < 4; nt++) acc[mt][nt] = zero;

    gload16(Xa + (size_t)(row0 + wave * 16 + srow) * DMODEL + scol, lA[0] + wave * 512);
#pragma unroll
    for (int j = 0; j < 2; j++) {
        const int seg = wave * 2 + j;
        gload16(Wt + (size_t)(col0 + seg * 16 + srow) * DMODEL + scol, lB[0] + seg * 512);
    }

    for (int it = 0; it < 32; it++) {
        __syncthreads();
        const int cur = it & 1;
        if (it + 1 < 32) {
            const int k1 = (it + 1) * 32;
            const int nb = cur ^ 1;
            gload16(Xa + (size_t)(row0 + wave * 16 + srow) * DMODEL + k1 + scol, lA[nb] + wave * 512);
#pragma unroll
            for (int j = 0; j < 2; j++) {
                const int seg = wave * 2 + j;
                gload16(Wt + (size_t)(col0 + seg * 16 + srow) * DMODEL + k1 + scol, lB[nb] + seg * 512);
            }
        }
        bf16x8 aF[2], bF[4];
#pragma unroll
        for (int t = 0; t < 2; t++)
            aF[t] = *(const bf16x8*)(lA[cur] + (wm * 32 + t * 16 + l15) * 32 + quad * 8);
#pragma unroll
        for (int t = 0; t < 4; t++)
            bF[t] = *(const bf16x8*)(lB[cur] + (wn * 64 + t * 16 + l15) * 32 + quad * 8);
#pragma unroll
        for (int mt = 0; mt < 2; mt++)
#pragma unroll
            for (int nt = 0; nt < 4; nt++)
                acc[mt][nt] = MFMA_BF16(aF[mt], bF[nt], acc[mt][nt]);
    }

#pragma unroll
    for (int nt = 0; nt < 4; nt++) {
        const int gn = col0 + wn * 64 + nt * 16 + l15;
        const float bb = bias[gn];
#pragma unroll
        for (int mt = 0; mt < 2; mt++) {
#pragma unroll
            for (int r = 0; r < 4; r++) {
                const int tok = row0 + wm * 32 + mt * 16 + quad * 4 + r;
                out[(size_t)tok * DMODEL + gn] = acc[mt][nt][r] + bb;
            }
        }
    }
}

// ---------------- causal flash attention: 4 q-tiles per block (v6) ----------
// R0-R4 ledger: occupancy 2x -> null; reg prefetch (VGPR 92, real) -> null; VALU cut -> null.
// All consistent with vector-memory REQUEST-THROUGHPUT bound: each K/V frag load touches 16
// discontiguous 64B rows (~16 TA cycles), and total request count was invariant. v6 halves
// it: each block owns 4 q-tiles {2j,2j+1,62-2j,63-2j} (66 chunk-computes/block, balanced),
// so each loaded K/V chunk feeds 2x the MFMA. Grid 1024, single-buffered loads (R4: prefetch
// null), (256,2) for register room, fast/mask wave-uniform split + exp2 retained.
#define SHUF_PV(pk, Vv, oacc) do {                                                     \
    u32 a0 = __shfl(pk.u[0], srcA), a1 = __shfl(pk.u[1], srcA);                        \
    u32 a2 = __shfl(pk.u[0], srcB), a3 = __shfl(pk.u[1], srcB);                        \
    u32 b0 = __shfl(pk.u[2], srcA), b1 = __shfl(pk.u[3], srcA);                        \
    u32 b2 = __shfl(pk.u[2], srcB), b3 = __shfl(pk.u[3], srcB);                        \
    union { u32 u[4]; bf16x8 v; } bP;                                                  \
    bP.u[0] = hiP ? b0 : a0; bP.u[1] = hiP ? b1 : a1;                                  \
    bP.u[2] = hiP ? b2 : a2; bP.u[3] = hiP ? b3 : a3;                                  \
    __builtin_amdgcn_s_setprio(1);                                                     \
    _Pragma("unroll") for (int dt = 0; dt < 4; dt++)                                   \
        oacc[dt] = MFMA_BF16(Vv[dt], bP.v, oacc[dt]);                                  \
    __builtin_amdgcn_s_setprio(0);                                                     \
} while (0)

#define SOFTMAX_PV_FAST(S0x, S1x, Vv, lacc, oacc) do {                                 \
    float ps = 0.f;                                                                    \
    union { bf16_t hh2[8]; u32 u[4]; } pk;                                             \
    _Pragma("unroll") for (int r = 0; r < 4; r++) {                                    \
        float e0 = EXP2F(S0x[r]), e1 = EXP2F(S1x[r]);                                  \
        ps += e0 + e1;                                                                 \
        pk.hh2[r] = (bf16_t)e0; pk.hh2[4 + r] = (bf16_t)e1;                            \
    }                                                                                  \
    lacc += ps;                                                                        \
    SHUF_PV(pk, Vv, oacc);                                                             \
} while (0)

#define SOFTMAX_PV_MASK(S0x, S1x, Vv, kbv, qrow, lacc, oacc) do {                      \
    float ps = 0.f;                                                                    \
    union { bf16_t hh2[8]; u32 u[4]; } pk;                                             \
    _Pragma("unroll") for (int r = 0; r < 4; r++) {                                    \
        const int key0 = (kbv) + quad * 4 + r;                                         \
        float s0 = (key0 <= (qrow))      ? S0x[r] : -1e30f;                            \
        float s1 = (key0 + 16 <= (qrow)) ? S1x[r] : -1e30f;                            \
        float e0 = EXP2F(s0), e1 = EXP2F(s1);                                          \
        ps += e0 + e1;                                                                 \
        pk.hh2[r] = (bf16_t)e0; pk.hh2[4 + r] = (bf16_t)e1;                            \
    }                                                                                  \
    lacc += ps;                                                                        \
    SHUF_PV(pk, Vv, oacc);                                                             \
} while (0)

#define LOAD_KV(K0v, K1v, Vv, kbv) do {                                                \
    _Pragma("unroll") for (int c = 0; c < 2; c++) {                                    \
        K0v[c] = *(const bf16x8*)(Kp + (size_t)((kbv) + l15) * HDIM + c * 32 + quad * 8);      \
        K1v[c] = *(const bf16x8*)(Kp + (size_t)((kbv) + 16 + l15) * HDIM + c * 32 + quad * 8); \
    }                                                                                  \
    _Pragma("unroll") for (int dt = 0; dt < 4; dt++)                                   \
        Vv[dt] = *(const bf16x8*)(Vp + (size_t)(dt * 16 + l15) * SEQLEN + (kbv) + quad * 8);   \
} while (0)

__global__ __launch_bounds__(256, 2) void attn(
    const bf16_t* __restrict__ Qh, const bf16_t* __restrict__ Kh,
    const bf16_t* __restrict__ Vt, bf16_t* __restrict__ X)
{
    __shared__ __align__(8) float comb[2][64][68];     // partial publish: 4 tiles x 16 o + 4 l
    const int wave = threadIdx.x >> 6, lane = threadIdx.x & 63;
    const int quad = lane >> 4, l15 = lane & 15;
    const int L = blockIdx.x;                          // [0,1024)
    const int bh = (L & 7) * 8 + ((L >> 3) & 7);       // 8 heads per XCD
    const int j  = L >> 6;                             // quad-tile index [0,16)
    const int b = bh >> 4, h = bh & 15;

    // tiles: near pair 2j, 2j+1; far pair 62-2j, 63-2j  (66 chunk-computes/block, balanced)
    const int qbase0 = 32 * j,        qbase1 = 32 * j + 16;
    const int qbase2 = 992 - 32 * j,  qbase3 = 1008 - 32 * j;
    const int qrow0 = qbase0 + l15, qrow1 = qbase1 + l15;
    const int qrow2 = qbase2 + l15, qrow3 = qbase3 + l15;
    const int NKA = j + 1, NKB = 32 - j;               // chunks needed by near / far pairs

    const bf16_t* Qp = Qh + (size_t)bh * SEQLEN * HDIM;
    const bf16_t* Kp = Kh + (size_t)bh * SEQLEN * HDIM;
    const bf16_t* Vp = Vt + (size_t)bh * HDIM * SEQLEN;

    bf16x8 bQ0[2], bQ1[2], bQ2[2], bQ3[2];
#pragma unroll
    for (int c = 0; c < 2; c++) {
        bQ0[c] = *(const bf16x8*)(Qp + (size_t)qrow0 * HDIM + c * 32 + quad * 8);
        bQ1[c] = *(const bf16x8*)(Qp + (size_t)qrow1 * HDIM + c * 32 + quad * 8);
        bQ2[c] = *(const bf16x8*)(Qp + (size_t)qrow2 * HDIM + c * 32 + quad * 8);
        bQ3[c] = *(const bf16x8*)(Qp + (size_t)qrow3 * HDIM + c * 32 + quad * 8);
    }

    const floatx4 zero = {0.f, 0.f, 0.f, 0.f};
    float l0_ = 0.f, l1_ = 0.f, l2_ = 0.f, l3_ = 0.f;
    floatx4 o0[4], o1[4], o2[4], o3[4];
#pragma unroll
    for (int dt = 0; dt < 4; dt++) { o0[dt] = zero; o1[dt] = zero; o2[dt] = zero; o3[dt] = zero; }

    const int srcA = ((quad & 1) ? 32 : 0) + l15;      // P-transpose shuffle sources
    const int srcB = srcA + 16;
    const bool hiP = (quad >= 2);

    for (int kc = wave; kc < NKB; kc += 4) {
        const int kb = kc * 32;
        bf16x8 K0[2], K1[2], Vv[4];
        LOAD_KV(K0, K1, Vv, kb);

        const bool doA = (kc < NKA);                   // wave-uniform
        floatx4 S0_0 = zero, S1_0 = zero, S0_1 = zero, S1_1 = zero;
        floatx4 S0_2 = zero, S1_2 = zero, S0_3 = zero, S1_3 = zero;
        __builtin_amdgcn_s_setprio(1);
#pragma unroll
        for (int c = 0; c < 2; c++) {
            S0_2 = MFMA_BF16(K0[c], bQ2[c], S0_2);
            S1_2 = MFMA_BF16(K1[c], bQ2[c], S1_2);
            S0_3 = MFMA_BF16(K0[c], bQ3[c], S0_3);
            S1_3 = MFMA_BF16(K1[c], bQ3[c], S1_3);
        }
        __builtin_amdgcn_s_setprio(0);
        if (doA) {
            __builtin_amdgcn_s_setprio(1);
#pragma unroll
            for (int c = 0; c < 2; c++) {
                S0_0 = MFMA_BF16(K0[c], bQ0[c], S0_0);
                S1_0 = MFMA_BF16(K1[c], bQ0[c], S1_0);
                S0_1 = MFMA_BF16(K0[c], bQ1[c], S0_1);
                S1_1 = MFMA_BF16(K1[c], bQ1[c], S1_1);
            }
            __builtin_amdgcn_s_setprio(0);
        }
        if (kb + 31 <= qbase2) { SOFTMAX_PV_FAST(S0_2, S1_2, Vv, l2_, o2); }
        else                   { SOFTMAX_PV_MASK(S0_2, S1_2, Vv, kb, qrow2, l2_, o2); }
        if (kb + 31 <= qbase3) { SOFTMAX_PV_FAST(S0_3, S1_3, Vv, l3_, o3); }
        else                   { SOFTMAX_PV_MASK(S0_3, S1_3, Vv, kb, qrow3, l3_, o3); }
        if (doA) {
            if (kb + 31 <= qbase0) { SOFTMAX_PV_FAST(S0_0, S1_0, Vv, l0_, o0); }
            else                   { SOFTMAX_PV_MASK(S0_0, S1_0, Vv, kb, qrow0, l0_, o0); }
            if (kb + 31 <= qbase1) { SOFTMAX_PV_FAST(S0_1, S1_1, Vv, l1_, o1); }
            else                   { SOFTMAX_PV_MASK(S0_1, S1_1, Vv, kb, qrow1, l1_, o1); }
        }
    }

    // 2-stage partial combine through LDS: waves 1,3 -> 0,2; then wave 2 -> 0.
    auto publish = [&](int slot) {
        float2* d2 = (float2*)&comb[slot][lane][0];
#pragma unroll
        for (int dt = 0; dt < 4; dt++) {
            d2[ 0 + 2 * dt]     = make_float2(o0[dt][0], o0[dt][1]);
            d2[ 0 + 2 * dt + 1] = make_float2(o0[dt][2], o0[dt][3]);
            d2[ 8 + 2 * dt]     = make_float2(o1[dt][0], o1[dt][1]);
            d2[ 8 + 2 * dt + 1] = make_float2(o1[dt][2], o1[dt][3]);
            d2[16 + 2 * dt]     = make_float2(o2[dt][0], o2[dt][1]);
            d2[16 + 2 * dt + 1] = make_float2(o2[dt][2], o2[dt][3]);
            d2[24 + 2 * dt]     = make_float2(o3[dt][0], o3[dt][1]);
            d2[24 + 2 * dt + 1] = make_float2(o3[dt][2], o3[dt][3]);
        }
        d2[32] = make_float2(l0_, l1_);
        d2[33] = make_float2(l2_, l3_);
    };
    auto accum = [&](int slot) {
        const float2* s2 = (const float2*)&comb[slot][lane][0];
#pragma unroll
        for (int dt = 0; dt < 4; dt++) {
            float2 p0 = s2[ 0 + 2 * dt], p1 = s2[ 0 + 2 * dt + 1];
            float2 q0 = s2[ 8 + 2 * dt], q1 = s2[ 8 + 2 * dt + 1];
            float2 r0 = s2[16 + 2 * dt], r1 = s2[16 + 2 * dt + 1];
            float2 t0 = s2[24 + 2 * dt], t1 = s2[24 + 2 * dt + 1];
            o0[dt][0] += p0.x; o0[dt][1] += p0.y; o0[dt][2] += p1.x; o0[dt][3] += p1.y;
            o1[dt][0] += q0.x; o1[dt][1] += q0.y; o1[dt][2] += q1.x; o1[dt][3] += q1.y;
            o2[dt][0] += r0.x; o2[dt][1] += r0.y; o2[dt][2] += r1.x; o2[dt][3] += r1.y;
            o3[dt][0] += t0.x; o3[dt][1] += t0.y; o3[dt][2] += t1.x; o3[dt][3] += t1.y;
        }
        float2 la = s2[32], lb = s2[33];
        l0_ += la.x; l1_ += la.y; l2_ += lb.x; l3_ += lb.y;
    };

    if (wave & 1) publish(wave >> 1);                  // 1 -> slot 0, 3 -> slot 1
    __syncthreads();
    if (!(wave & 1)) accum(wave >> 1);                 // 0 += slot 0, 2 += slot 1
    __syncthreads();
    if (wave == 2) publish(0);
    __syncthreads();
    if (wave == 0) {
        accum(0);

        l0_ += __shfl_xor(l0_, 16); l0_ += __shfl_xor(l0_, 32);
        l1_ += __shfl_xor(l1_, 16); l1_ += __shfl_xor(l1_, 32);
        l2_ += __shfl_xor(l2_, 16); l2_ += __shfl_xor(l2_, 32);
        l3_ += __shfl_xor(l3_, 16); l3_ += __shfl_xor(l3_, 32);

        const float i0 = 1.f / l0_, i1 = 1.f / l1_, i2 = 1.f / l2_, i3 = 1.f / l3_;
#pragma unroll
        for (int dt = 0; dt < 4; dt++) {
            bf16x4 v0, v1, v2, v3;
#pragma unroll
            for (int r = 0; r < 4; r++) {
                v0[r] = (bf16_t)(o0[dt][r] * i0);
                v1[r] = (bf16_t)(o1[dt][r] * i1);
                v2[r] = (bf16_t)(o2[dt][r] * i2);
                v3[r] = (bf16_t)(o3[dt][r] * i3);
            }
            const size_t cofs = (size_t)h * HDIM + dt * 16 + quad * 4;
            *(bf16x4*)(&X[((size_t)(b * SEQLEN + qrow0)) * DMODEL + cofs]) = v0;
            *(bf16x4*)(&X[((size_t)(b * SEQLEN + qrow1)) * DMODEL + cofs]) = v1;
            *(bf16x4*)(&X[((size_t)(b * SEQLEN + qrow2)) * DMODEL + cofs]) = v2;
            *(bf16x4*)(&X[((size_t)(b * SEQLEN + qrow3)) * DMODEL + cofs]) = v3;
        }
    }
}

extern "C" void kernel_launch(void* const* d_in, const int* in_sizes, int n_in,
                              void* d_out, int out_size, void* d_ws, size_t ws_size,
                              hipStream_t stream)
{
    const float* q  = (const float*)d_in[0];
    const float* k  = (const float*)d_in[1];
    const float* v  = (const float*)d_in[2];
    // d_in[3] = causal mask (deterministic tril) — applied analytically
    const float* Wq = (const float*)d_in[4];
    const float* bq = (const float*)d_in[5];
    const float* Wk = (const float*)d_in[6];
    const float* bk = (const float*)d_in[7];
    const float* Wv = (const float*)d_in[8];
    const float* bv = (const float*)d_in[9];
    const float* Wo = (const float*)d_in[10];
    const float* bo = (const float*)d_in[11];
    float* out = (float*)d_out;

    char* ws = (char*)d_ws;
    const size_t MB = 1ull << 20;
    const size_t NELEM = (size_t)NTOK * DMODEL;            // 4M elements / 8 MB bf16
    bf16_t* Wt = (bf16_t*)ws;                              // [0,8) MB
    bf16_t* Qh = (bf16_t*)(ws + 8 * MB);                   // [8,16)
    bf16_t* Kh = (bf16_t*)(ws + 16 * MB);                  // [16,24)
    bf16_t* Vt = (bf16_t*)(ws + 24 * MB);                  // [24,32)
    bf16_t* Xr = (bf16_t*)(ws + 32 * MB);                  // [32,...) staging; Xa overlays

    if (ws_size >= 56 * MB) {
        prep<<<dim3(32, 32, 7), dim3(256), 0, stream>>>(Wq, Wk, Wv, Wo, q, k, v, Wt, Xr);
        gemm_qkv<<<dim3(32, 8, 3), dim3(256), 0, stream>>>(
            Xr, NELEM, 0, Wt, bq, bk, bv, Qh, Kh, Vt);
    } else {
        transpose_w<<<dim3(32, 32, 4), dim3(32, 8), 0, stream>>>(Wq, Wk, Wv, Wo, Wt);
        const float* qkv_in[3] = {q, k, v};
        for (int m = 0; m < 3; m++) {
            cvt_bf16<<<dim3(2048), dim3(256), 0, stream>>>(qkv_in[m], Xr);
            gemm_qkv<<<dim3(32, 8, 1), dim3(256), 0, stream>>>(
                Xr, 0, m, Wt, bq, bk, bv, Qh, Kh, Vt);
        }
    }

    bf16_t* Xa = Xr;   // overlay q's bf16 copy (dead after gemm_qkv)
    attn<<<dim3(1024), dim3(256), 0, stream>>>(Qh, Kh, Vt, Xa);
    gemm_o<<<dim3(64, 8), dim3(256), 0, stream>>>(
        Xa, Wt + 3 * (size_t)DMODEL * DMODEL, bo, out);
}

// Round 6
// 210.410 us; speedup vs baseline: 1.6246x; 1.0453x over previous
//
#include <hip/hip_runtime.h>
#include <math.h>

typedef __bf16 bf16_t;
typedef bf16_t bf16x8 __attribute__((ext_vector_type(8)));
typedef bf16_t bf16x4 __attribute__((ext_vector_type(4)));
typedef float  floatx4 __attribute__((ext_vector_type(4)));
typedef unsigned int u32;

#define MFMA_BF16(a, b, c) __builtin_amdgcn_mfma_f32_16x16x32_bf16((a), (b), (c), 0, 0, 0)

#if __has_builtin(__builtin_amdgcn_exp2f)
#define EXP2F(x) __builtin_amdgcn_exp2f(x)
#else
#define EXP2F(x) exp2f(x)
#endif

static constexpr int DMODEL = 1024;
static constexpr int NHEAD  = 16;
static constexpr int HDIM   = 64;
static constexpr int NBATCH = 4;
static constexpr int SEQLEN = 1024;
static constexpr int NTOK   = NBATCH * SEQLEN;  // 4096

typedef __attribute__((address_space(3))) void       as3_void;
typedef __attribute__((address_space(1))) const void as1_cvoid;

// async global->LDS, 16B/lane; LDS dest = wave-uniform base + lane*16
__device__ __forceinline__ void gload16(const void* g, void* l) {
    __builtin_amdgcn_global_load_lds((as1_cvoid*)g, (as3_void*)l, 16, 0, 0);
}

// load 8 consecutive fp32, round to bf16x8
__device__ __forceinline__ bf16x8 load_cvt8(const float* __restrict__ p) {
    floatx4 a = *(const floatx4*)p;
    floatx4 b = *(const floatx4*)(p + 4);
    bf16x8 r;
    r[0] = (bf16_t)a[0]; r[1] = (bf16_t)a[1]; r[2] = (bf16_t)a[2]; r[3] = (bf16_t)a[3];
    r[4] = (bf16_t)b[0]; r[5] = (bf16_t)b[1]; r[6] = (bf16_t)b[2]; r[7] = (bf16_t)b[3];
    return r;
}

// ---------------- fused prep: z=0..3 transpose+cvt W_z; z=4..6 cvt q/k/v ----------------
__global__ __launch_bounds__(256) void prep(
    const float* __restrict__ W0, const float* __restrict__ W1,
    const float* __restrict__ W2, const float* __restrict__ W3,
    const float* __restrict__ q, const float* __restrict__ k, const float* __restrict__ v,
    bf16_t* __restrict__ Wt, bf16_t* __restrict__ Xr)
{
    __shared__ float tile[32][33];
    const int z = blockIdx.z;
    if (z < 4) {
        const float* W = (z == 0) ? W0 : (z == 1) ? W1 : (z == 2) ? W2 : W3;
        bf16_t* O = Wt + (size_t)z * DMODEL * DMODEL;
        const int tx = threadIdx.x & 31, ty = threadIdx.x >> 5;   // 32 x 8
        const int r0 = blockIdx.x * 32, c0 = blockIdx.y * 32;
#pragma unroll
        for (int i = 0; i < 32; i += 8)
            tile[ty + i][tx] = W[(size_t)(r0 + ty + i) * DMODEL + c0 + tx];
        __syncthreads();
#pragma unroll
        for (int i = 0; i < 32; i += 8)
            O[(size_t)(c0 + ty + i) * DMODEL + r0 + tx] = (bf16_t)tile[tx][ty + i];
    } else {
        const float* src = (z == 4) ? q : (z == 5) ? k : v;
        bf16_t* dst = Xr + (size_t)(z - 4) * ((size_t)NTOK * DMODEL);
        size_t i = (((size_t)blockIdx.y * 32 + blockIdx.x) * 256 + threadIdx.x) * 16;
        *(bf16x8*)(dst + i)     = load_cvt8(src + i);
        *(bf16x8*)(dst + i + 8) = load_cvt8(src + i + 8);
    }
}

// ---------------- fallback-path kernels (ws < 56 MB) ----------------
__global__ __launch_bounds__(256) void transpose_w(
    const float* __restrict__ W0, const float* __restrict__ W1,
    const float* __restrict__ W2, const float* __restrict__ W3,
    bf16_t* __restrict__ out)
{
    __shared__ float tile[32][33];
    const float* W = (blockIdx.z == 0) ? W0 : (blockIdx.z == 1) ? W1
                   : (blockIdx.z == 2) ? W2 : W3;
    bf16_t* O = out + (size_t)blockIdx.z * DMODEL * DMODEL;
    int tx = threadIdx.x, ty = threadIdx.y;           // 32 x 8
    int r0 = blockIdx.x * 32, c0 = blockIdx.y * 32;
#pragma unroll
    for (int i = 0; i < 32; i += 8)
        tile[ty + i][tx] = W[(size_t)(r0 + ty + i) * DMODEL + c0 + tx];
    __syncthreads();
#pragma unroll
    for (int i = 0; i < 32; i += 8)
        O[(size_t)(c0 + ty + i) * DMODEL + r0 + tx] = (bf16_t)tile[tx][ty + i];
}
__global__ __launch_bounds__(256) void cvt_bf16(
    const float* __restrict__ src, bf16_t* __restrict__ dst)
{
    size_t i = ((size_t)blockIdx.x * 256 + threadIdx.x) * 8;
    *(bf16x8*)(dst + i) = load_cvt8(src + i);
}

// ---------------- QKV projection GEMM, 128x128 tile, BK=32, dbuf single-barrier ----------------
// v7: (1) K-loop fully unrolled: k-advance folds into load/ds immediate offsets (K range
// = 2048B fits imm13), buffer select static -> kills the per-iter address VALU that made
// VALUBusy(37%) exceed MfmaUtil(20%). (2) MFMA operands swapped (acc = B^T*A^T = C^T):
// each thread holds 4 consecutive output features -> bf16x4 stores for Q/K (4x fewer
// store instrs), 4x32B-coalesced V-transpose stores (was 64 scattered 2B segs/instr).
__global__ __launch_bounds__(256) void gemm_qkv(
    const bf16_t* __restrict__ Xb, size_t astride, int mode0,
    const bf16_t* __restrict__ Wt,
    const float* __restrict__ bq, const float* __restrict__ bk, const float* __restrict__ bv,
    bf16_t* __restrict__ Qh, bf16_t* __restrict__ Kh, bf16_t* __restrict__ Vt)
{
    const int mode = mode0 + blockIdx.z;
    const bf16_t* A = Xb + astride * (size_t)blockIdx.z;
    const bf16_t* B = Wt + (size_t)mode * DMODEL * DMODEL;
    const float* bias = (mode == 0) ? bq : (mode == 1) ? bk : bv;
    bf16_t* out       = (mode == 0) ? Qh : (mode == 1) ? Kh : Vt;

    __shared__ __align__(16) bf16_t lA[2][128 * 32];
    __shared__ __align__(16) bf16_t lB[2][128 * 32];

    const int wave = threadIdx.x >> 6, lane = threadIdx.x & 63;
    const int quad = lane >> 4, l15 = lane & 15;
    const int wm = wave >> 1, wn = wave & 1;
    const int row0 = blockIdx.x * 128, col0 = blockIdx.y * 128;
    const int srow = lane >> 2, scol = (lane & 3) * 8;

    const floatx4 zero = {0.f, 0.f, 0.f, 0.f};
    floatx4 acc[4][4];
#pragma unroll
    for (int mt = 0; mt < 4; mt++)
#pragma unroll
        for (int nt = 0; nt < 4; nt++) acc[mt][nt] = zero;

    const bf16_t* Abase = A + (size_t)(row0 + srow) * DMODEL + scol;
    const bf16_t* Bbase = B + (size_t)(col0 + srow) * DMODEL + scol;

#pragma unroll
    for (int j = 0; j < 2; j++) {
        const int seg = j * 4 + wave;
        gload16(Abase + (size_t)seg * 16 * DMODEL, lA[0] + seg * 512);
        gload16(Bbase + (size_t)seg * 16 * DMODEL, lB[0] + seg * 512);
    }

#pragma unroll
    for (int it = 0; it < 32; it++) {
        __syncthreads();
        const int cur = it & 1;
        if (it + 1 < 32) {
            const int k1 = (it + 1) * 32;
            const int nb = cur ^ 1;
#pragma unroll
            for (int j = 0; j < 2; j++) {
                const int seg = j * 4 + wave;
                gload16(Abase + (size_t)seg * 16 * DMODEL + k1, lA[nb] + seg * 512);
                gload16(Bbase + (size_t)seg * 16 * DMODEL + k1, lB[nb] + seg * 512);
            }
        }
        bf16x8 aF[4], bF[4];
#pragma unroll
        for (int t = 0; t < 4; t++) {
            aF[t] = *(const bf16x8*)(lA[cur] + (wm * 64 + t * 16 + l15) * 32 + quad * 8);
            bF[t] = *(const bf16x8*)(lB[cur] + (wn * 64 + t * 16 + l15) * 32 + quad * 8);
        }
#pragma unroll
        for (int mt = 0; mt < 4; mt++)
#pragma unroll
            for (int nt = 0; nt < 4; nt++)
                acc[mt][nt] = MFMA_BF16(bF[nt], aF[mt], acc[mt][nt]);   // C^T: rows=gn, cols=tok
    }

    // epilogue: thread holds gn = col0+wn*64+nt*16+quad*4+{0..3} (rows), tok = ...+l15 (col)
    const int hh = (col0 + wn * 64) >> 6;              // head (64-col aligned)
#pragma unroll
    for (int nt = 0; nt < 4; nt++) {
        const int gn0 = col0 + wn * 64 + nt * 16 + quad * 4;
        const floatx4 bb = *(const floatx4*)&bias[gn0];
        const int dd0 = (wn * 64 + nt * 16 + quad * 4) & 63;
#pragma unroll
        for (int mt = 0; mt < 4; mt++) {
            const int tok = row0 + wm * 64 + mt * 16 + l15;
            const int b = tok >> 10, s = tok & 1023;
            if (mode == 2) {
#pragma unroll
                for (int r = 0; r < 4; r++)
                    Vt[((size_t)((b * NHEAD + hh) * HDIM + dd0 + r)) * SEQLEN + s] =
                        (bf16_t)(acc[mt][nt][r] + bb[r]);
            } else {
                bf16x4 v;
#pragma unroll
                for (int r = 0; r < 4; r++) {
                    float vv = acc[mt][nt][r] + bb[r];
                    // Q: fold 1/sqrt(Dk) AND log2(e) so softmax uses raw exp2
                    if (mode == 0) vv *= 0.1803368801111204f;
                    v[r] = (bf16_t)vv;
                }
                *(bf16x4*)&out[((size_t)((b * NHEAD + hh) * SEQLEN + s)) * HDIM + dd0] = v;
            }
        }
    }
}

// ---------------- output projection GEMM, 64x128 tile, dbuf single-barrier ----------------
// v7: unrolled K-loop + swapped operands -> floatx4 (full 64B line per quad-group) stores.
__global__ __launch_bounds__(256) void gemm_o(
    const bf16_t* __restrict__ Xa, const bf16_t* __restrict__ Wt,
    const float* __restrict__ bias, float* __restrict__ out)
{
    __shared__ __align__(16) bf16_t lA[2][64 * 32];
    __shared__ __align__(16) bf16_t lB[2][128 * 32];

    const int wave = threadIdx.x >> 6, lane = threadIdx.x & 63;
    const int quad = lane >> 4, l15 = lane & 15;
    const int wm = wave & 1, wn = wave >> 1;
    const int row0 = blockIdx.x * 64, col0 = blockIdx.y * 128;
    const int srow = lane >> 2, scol = (lane & 3) * 8;

    const floatx4 zero = {0.f, 0.f, 0.f, 0.f};
    floatx4 acc[2][4];
#pragma unroll
    for (int mt = 0; mt < 2; mt++)
#pragma unroll
        for (int nt = 0; nt < 4; nt++) acc[mt][nt] = zero;

    const bf16_t* Abase = Xa + (size_t)(row0 + srow) * DMODEL + scol;
    const bf16_t* Bbase = Wt + (size_t)(col0 + srow) * DMODEL + scol;

    gload16(Abase + (size_t)wave * 16 * DMODEL, lA[0] + wave * 512);
#pragma unroll
    for (int j = 0; j < 2; j++) {
        const int seg = wave * 2 + j;
        gload16(Bbase + (size_t)seg * 16 * DMODEL, lB[0] + seg * 512);
    }

#pragma unroll
    for (int it = 0; it < 32; it++) {
        __syncthreads();
        const int cur = it & 1;
        if (it + 1 < 32) {
            const int k1 = (it + 1) * 32;
            const int nb = cur ^ 1;
            gload16(Abase + (size_t)wave * 16 * DMODEL + k1, lA[nb] + wave * 512);
#pragma unroll
            for (int j = 0; j < 2; j++) {
                const int seg = wave * 2 + j;
                gload16(Bbase + (size_t)seg * 16 * DMODEL + k1, lB[nb] + seg * 512);
            }
        }
        bf16x8 aF[2], bF[4];
#pragma unroll
        for (int t = 0; t < 2; t++)
            aF[t] = *(const bf16x8*)(lA[cur] + (wm * 32 + t * 16 + l15) * 32 + quad * 8);
#pragma unroll
        for (int t = 0; t < 4; t++)
            bF[t] = *(const bf16x8*)(lB[cur] + (wn * 64 + t * 16 + l15) * 32 + quad * 8);
#pragma unroll
        for (int mt = 0; mt < 2; mt++)
#pragma unroll
            for (int nt = 0; nt < 4; nt++)
                acc[mt][nt] = MFMA_BF16(bF[nt], aF[mt], acc[mt][nt]);   // C^T
    }

#pragma unroll
    for (int nt = 0; nt < 4; nt++) {
        const int gn0 = col0 + wn * 64 + nt * 16 + quad * 4;
        const floatx4 bb = *(const floatx4*)&bias[gn0];
#pragma unroll
        for (int mt = 0; mt < 2; mt++) {
            const int tok = row0 + wm * 32 + mt * 16 + l15;
            floatx4 v;
#pragma unroll
            for (int r = 0; r < 4; r++) v[r] = acc[mt][nt][r] + bb[r];
            *(floatx4*)&out[(size_t)tok * DMODEL + gn0] = v;
        }
    }
}

// ---------------- causal flash attention: 4 q-tiles per block (v6, unchanged) ----------
#define SHUF_PV(pk, Vv, oacc) do {                                                     \
    u32 a0 = __shfl(pk.u[0], srcA), a1 = __shfl(pk.u[1], srcA);                        \
    u32 a2 = __shfl(pk.u[0], srcB), a3 = __shfl(pk.u[1], srcB);                        \
    u32 b0 = __shfl(pk.u[2], srcA), b1 = __shfl(pk.u[3], srcA);                        \
    u32 b2 = __shfl(pk.u[2], srcB), b3 = __shfl(pk.u[3], srcB);                        \
    union { u32 u[4]; bf16x8 v; } bP;                                                  \
    bP.u[0] = hiP ? b0 : a0; bP.u[1] = hiP ? b1 : a1;                                  \
    bP.u[2] = hiP ? b2 : a2; bP.u[3] = hiP ? b3 : a3;                                  \
    __builtin_amdgcn_s_setprio(1);                                                     \
    _Pragma("unroll") for (int dt = 0; dt < 4; dt++)                                   \
        oacc[dt] = MFMA_BF16(Vv[dt], bP.v, oacc[dt]);                                  \
    __builtin_amdgcn_s_setprio(0);                                                     \
} while (0)

#define SOFTMAX_PV_FAST(S0x, S1x, Vv, lacc, oacc) do {                                 \
    float ps = 0.f;                                                                    \
    union { bf16_t hh2[8]; u32 u[4]; } pk;                                             \
    _Pragma("unroll") for (int r = 0; r < 4; r++) {                                    \
        float e0 = EXP2F(S0x[r]), e1 = EXP2F(S1x[r]);                                  \
        ps += e0 + e1;                                                                 \
        pk.hh2[r] = (bf16_t)e0; pk.hh2[4 + r] = (bf16_t)e1;                            \
    }                                                                                  \
    lacc += ps;                                                                        \
    SHUF_PV(pk, Vv, oacc);                                                             \
} while (0)

#define SOFTMAX_PV_MASK(S0x, S1x, Vv, kbv, qrow, lacc, oacc) do {                      \
    float ps = 0.f;                                                                    \
    union { bf16_t hh2[8]; u32 u[4]; } pk;                                             \
    _Pragma("unroll") for (int r = 0; r < 4; r++) {                                    \
        const int key0 = (kbv) + quad * 4 + r;                                         \
        float s0 = (key0 <= (qrow))      ? S0x[r] : -1e30f;                            \
        float s1 = (key0 + 16 <= (qrow)) ? S1x[r] : -1e30f;                            \
        float e0 = EXP2F(s0), e1 = EXP2F(s1);                                          \
        ps += e0 + e1;                                                                 \
        pk.hh2[r] = (bf16_t)e0; pk.hh2[4 + r] = (bf16_t)e1;                            \
    }                                                                                  \
    lacc += ps;                                                                        \
    SHUF_PV(pk, Vv, oacc);                                                             \
} while (0)

#define LOAD_KV(K0v, K1v, Vv, kbv) do {                                                \
    _Pragma("unroll") for (int c = 0; c < 2; c++) {                                    \
        K0v[c] = *(const bf16x8*)(Kp + (size_t)((kbv) + l15) * HDIM + c * 32 + quad * 8);      \
        K1v[c] = *(const bf16x8*)(Kp + (size_t)((kbv) + 16 + l15) * HDIM + c * 32 + quad * 8); \
    }                                                                                  \
    _Pragma("unroll") for (int dt = 0; dt < 4; dt++)                                   \
        Vv[dt] = *(const bf16x8*)(Vp + (size_t)(dt * 16 + l15) * SEQLEN + (kbv) + quad * 8);   \
} while (0)

__global__ __launch_bounds__(256, 2) void attn(
    const bf16_t* __restrict__ Qh, const bf16_t* __restrict__ Kh,
    const bf16_t* __restrict__ Vt, bf16_t* __restrict__ X)
{
    __shared__ __align__(8) float comb[2][64][68];     // partial publish: 4 tiles x 16 o + 4 l
    const int wave = threadIdx.x >> 6, lane = threadIdx.x & 63;
    const int quad = lane >> 4, l15 = lane & 15;
    const int L = blockIdx.x;                          // [0,1024)
    const int bh = (L & 7) * 8 + ((L >> 3) & 7);       // 8 heads per XCD
    const int j  = L >> 6;                             // quad-tile index [0,16)
    const int b = bh >> 4, h = bh & 15;

    const int qbase0 = 32 * j,        qbase1 = 32 * j + 16;
    const int qbase2 = 992 - 32 * j,  qbase3 = 1008 - 32 * j;
    const int qrow0 = qbase0 + l15, qrow1 = qbase1 + l15;
    const int qrow2 = qbase2 + l15, qrow3 = qbase3 + l15;
    const int NKA = j + 1, NKB = 32 - j;               // chunks needed by near / far pairs

    const bf16_t* Qp = Qh + (size_t)bh * SEQLEN * HDIM;
    const bf16_t* Kp = Kh + (size_t)bh * SEQLEN * HDIM;
    const bf16_t* Vp = Vt + (size_t)bh * HDIM * SEQLEN;

    bf16x8 bQ0[2], bQ1[2], bQ2[2], bQ3[2];
#pragma unroll
    for (int c = 0; c < 2; c++) {
        bQ0[c] = *(const bf16x8*)(Qp + (size_t)qrow0 * HDIM + c * 32 + quad * 8);
        bQ1[c] = *(const bf16x8*)(Qp + (size_t)qrow1 * HDIM + c * 32 + quad * 8);
        bQ2[c] = *(const bf16x8*)(Qp + (size_t)qrow2 * HDIM + c * 32 + quad * 8);
        bQ3[c] = *(const bf16x8*)(Qp + (size_t)qrow3 * HDIM + c * 32 + quad * 8);
    }

    const floatx4 zero = {0.f, 0.f, 0.f, 0.f};
    float l0_ = 0.f, l1_ = 0.f, l2_ = 0.f, l3_ = 0.f;
    floatx4 o0[4], o1[4], o2[4], o3[4];
#pragma unroll
    for (int dt = 0; dt < 4; dt++) { o0[dt] = zero; o1[dt] = zero; o2[dt] = zero; o3[dt] = zero; }

    const int srcA = ((quad & 1) ? 32 : 0) + l15;      // P-transpose shuffle sources
    const int srcB = srcA + 16;
    const bool hiP = (quad >= 2);

    for (int kc = wave; kc < NKB; kc += 4) {
        const int kb = kc * 32;
        bf16x8 K0[2], K1[2], Vv[4];
        LOAD_KV(K0, K1, Vv, kb);

        const bool doA = (kc < NKA);                   // wave-uniform
        floatx4 S0_0 = zero, S1_0 = zero, S0_1 = zero, S1_1 = zero;
        floatx4 S0_2 = zero, S1_2 = zero, S0_3 = zero, S1_3 = zero;
        __builtin_amdgcn_s_setprio(1);
#pragma unroll
        for (int c = 0; c < 2; c++) {
            S0_2 = MFMA_BF16(K0[c], bQ2[c], S0_2);
            S1_2 = MFMA_BF16(K1[c], bQ2[c], S1_2);
            S0_3 = MFMA_BF16(K0[c], bQ3[c], S0_3);
            S1_3 = MFMA_BF16(K1[c], bQ3[c], S1_3);
        }
        __builtin_amdgcn_s_setprio(0);
        if (doA) {
            __builtin_amdgcn_s_setprio(1);
#pragma unroll
            for (int c = 0; c < 2; c++) {
                S0_0 = MFMA_BF16(K0[c], bQ0[c], S0_0);
                S1_0 = MFMA_BF16(K1[c], bQ0[c], S1_0);
                S0_1 = MFMA_BF16(K0[c], bQ1[c], S0_1);
                S1_1 = MFMA_BF16(K1[c], bQ1[c], S1_1);
            }
            __builtin_amdgcn_s_setprio(0);
        }
        if (kb + 31 <= qbase2) { SOFTMAX_PV_FAST(S0_2, S1_2, Vv, l2_, o2); }
        else                   { SOFTMAX_PV_MASK(S0_2, S1_2, Vv, kb, qrow2, l2_, o2); }
        if (kb + 31 <= qbase3) { SOFTMAX_PV_FAST(S0_3, S1_3, Vv, l3_, o3); }
        else                   { SOFTMAX_PV_MASK(S0_3, S1_3, Vv, kb, qrow3, l3_, o3); }
        if (doA) {
            if (kb + 31 <= qbase0) { SOFTMAX_PV_FAST(S0_0, S1_0, Vv, l0_, o0); }
            else                   { SOFTMAX_PV_MASK(S0_0, S1_0, Vv, kb, qrow0, l0_, o0); }
            if (kb + 31 <= qbase1) { SOFTMAX_PV_FAST(S0_1, S1_1, Vv, l1_, o1); }
            else                   { SOFTMAX_PV_MASK(S0_1, S1_1, Vv, kb, qrow1, l1_, o1); }
        }
    }

    // 2-stage partial combine through LDS: waves 1,3 -> 0,2; then wave 2 -> 0.
    auto publish = [&](int slot) {
        float2* d2 = (float2*)&comb[slot][lane][0];
#pragma unroll
        for (int dt = 0; dt < 4; dt++) {
            d2[ 0 + 2 * dt]     = make_float2(o0[dt][0], o0[dt][1]);
            d2[ 0 + 2 * dt + 1] = make_float2(o0[dt][2], o0[dt][3]);
            d2[ 8 + 2 * dt]     = make_float2(o1[dt][0], o1[dt][1]);
            d2[ 8 + 2 * dt + 1] = make_float2(o1[dt][2], o1[dt][3]);
            d2[16 + 2 * dt]     = make_float2(o2[dt][0], o2[dt][1]);
            d2[16 + 2 * dt + 1] = make_float2(o2[dt][2], o2[dt][3]);
            d2[24 + 2 * dt]     = make_float2(o3[dt][0], o3[dt][1]);
            d2[24 + 2 * dt + 1] = make_float2(o3[dt][2], o3[dt][3]);
        }
        d2[32] = make_float2(l0_, l1_);
        d2[33] = make_float2(l2_, l3_);
    };
    auto accum = [&](int slot) {
        const float2* s2 = (const float2*)&comb[slot][lane][0];
#pragma unroll
        for (int dt = 0; dt < 4; dt++) {
            float2 p0 = s2[ 0 + 2 * dt], p1 = s2[ 0 + 2 * dt + 1];
            float2 q0 = s2[ 8 + 2 * dt], q1 = s2[ 8 + 2 * dt + 1];
            float2 r0 = s2[16 + 2 * dt], r1 = s2[16 + 2 * dt + 1];
            float2 t0 = s2[24 + 2 * dt], t1 = s2[24 + 2 * dt + 1];
            o0[dt][0] += p0.x; o0[dt][1] += p0.y; o0[dt][2] += p1.x; o0[dt][3] += p1.y;
            o1[dt][0] += q0.x; o1[dt][1] += q0.y; o1[dt][2] += q1.x; o1[dt][3] += q1.y;
            o2[dt][0] += r0.x; o2[dt][1] += r0.y; o2[dt][2] += r1.x; o2[dt][3] += r1.y;
            o3[dt][0] += t0.x; o3[dt][1] += t0.y; o3[dt][2] += t1.x; o3[dt][3] += t1.y;
        }
        float2 la = s2[32], lb = s2[33];
        l0_ += la.x; l1_ += la.y; l2_ += lb.x; l3_ += lb.y;
    };

    if (wave & 1) publish(wave >> 1);                  // 1 -> slot 0, 3 -> slot 1
    __syncthreads();
    if (!(wave & 1)) accum(wave >> 1);                 // 0 += slot 0, 2 += slot 1
    __syncthreads();
    if (wave == 2) publish(0);
    __syncthreads();
    if (wave == 0) {
        accum(0);

        l0_ += __shfl_xor(l0_, 16); l0_ += __shfl_xor(l0_, 32);
        l1_ += __shfl_xor(l1_, 16); l1_ += __shfl_xor(l1_, 32);
        l2_ += __shfl_xor(l2_, 16); l2_ += __shfl_xor(l2_, 32);
        l3_ += __shfl_xor(l3_, 16); l3_ += __shfl_xor(l3_, 32);

        const float i0 = 1.f / l0_, i1 = 1.f / l1_, i2 = 1.f / l2_, i3 = 1.f / l3_;
#pragma unroll
        for (int dt = 0; dt < 4; dt++) {
            bf16x4 v0, v1, v2, v3;
#pragma unroll
            for (int r = 0; r < 4; r++) {
                v0[r] = (bf16_t)(o0[dt][r] * i0);
                v1[r] = (bf16_t)(o1[dt][r] * i1);
                v2[r] = (bf16_t)(o2[dt][r] * i2);
                v3[r] = (bf16_t)(o3[dt][r] * i3);
            }
            const size_t cofs = (size_t)h * HDIM + dt * 16 + quad * 4;
            *(bf16x4*)(&X[((size_t)(b * SEQLEN + qrow0)) * DMODEL + cofs]) = v0;
            *(bf16x4*)(&X[((size_t)(b * SEQLEN + qrow1)) * DMODEL + cofs]) = v1;
            *(bf16x4*)(&X[((size_t)(b * SEQLEN + qrow2)) * DMODEL + cofs]) = v2;
            *(bf16x4*)(&X[((size_t)(b * SEQLEN + qrow3)) * DMODEL + cofs]) = v3;
        }
    }
}

extern "C" void kernel_launch(void* const* d_in, const int* in_sizes, int n_in,
                              void* d_out, int out_size, void* d_ws, size_t ws_size,
                              hipStream_t stream)
{
    const float* q  = (const float*)d_in[0];
    const float* k  = (const float*)d_in[1];
    const float* v  = (const float*)d_in[2];
    // d_in[3] = causal mask (deterministic tril) — applied analytically
    const float* Wq = (const float*)d_in[4];
    const float* bq = (const float*)d_in[5];
    const float* Wk = (const float*)d_in[6];
    const float* bk = (const float*)d_in[7];
    const float* Wv = (const float*)d_in[8];
    const float* bv = (const float*)d_in[9];
    const float* Wo = (const float*)d_in[10];
    const float* bo = (const float*)d_in[11];
    float* out = (float*)d_out;

    char* ws = (char*)d_ws;
    const size_t MB = 1ull << 20;
    const size_t NELEM = (size_t)NTOK * DMODEL;            // 4M elements / 8 MB bf16
    bf16_t* Wt = (bf16_t*)ws;                              // [0,8) MB
    bf16_t* Qh = (bf16_t*)(ws + 8 * MB);                   // [8,16)
    bf16_t* Kh = (bf16_t*)(ws + 16 * MB);                  // [16,24)
    bf16_t* Vt = (bf16_t*)(ws + 24 * MB);                  // [24,32)
    bf16_t* Xr = (bf16_t*)(ws + 32 * MB);                  // [32,...) staging; Xa overlays

    if (ws_size >= 56 * MB) {
        prep<<<dim3(32, 32, 7), dim3(256), 0, stream>>>(Wq, Wk, Wv, Wo, q, k, v, Wt, Xr);
        gemm_qkv<<<dim3(32, 8, 3), dim3(256), 0, stream>>>(
            Xr, NELEM, 0, Wt, bq, bk, bv, Qh, Kh, Vt);
    } else {
        transpose_w<<<dim3(32, 32, 4), dim3(32, 8), 0, stream>>>(Wq, Wk, Wv, Wo, Wt);
        const float* qkv_in[3] = {q, k, v};
        for (int m = 0; m < 3; m++) {
            cvt_bf16<<<dim3(2048), dim3(256), 0, stream>>>(qkv_in[m], Xr);
            gemm_qkv<<<dim3(32, 8, 1), dim3(256), 0, stream>>>(
                Xr, 0, m, Wt, bq, bk, bv, Qh, Kh, Vt);
        }
    }

    bf16_t* Xa = Xr;   // overlay q's bf16 copy (dead after gemm_qkv)
    attn<<<dim3(1024), dim3(256), 0, stream>>>(Qh, Kh, Vt, Xa);
    gemm_o<<<dim3(64, 8), dim3(256), 0, stream>>>(
        Xa, Wt + 3 * (size_t)DMODEL * DMODEL, bo, out);
}